// Round 1
// baseline (7581.641 us; speedup 1.0000x reference)
//
#include <hip/hip_runtime.h>
#include <float.h>

#define B_ 32
#define C_ 128
#define N_ 883
#define T_ 12
#define K_ 706   // int(883*0.8)

#define SCALE_ 0.08838834764831845f  // 1/sqrt(128)

// 12-wide FMA into acc[] from three float4 loads
#define FMA12(a, h0, h1, h2) \
  acc[0] += (a)*(h0).x; acc[1] += (a)*(h0).y; acc[2] += (a)*(h0).z; acc[3] += (a)*(h0).w; \
  acc[4] += (a)*(h1).x; acc[5] += (a)*(h1).y; acc[6] += (a)*(h1).z; acc[7] += (a)*(h1).w; \
  acc[8] += (a)*(h2).x; acc[9] += (a)*(h2).y; acc[10] += (a)*(h2).z; acc[11] += (a)*(h2).w;

// ---------------- block reduction helpers (256 threads = 4 waves) ----------------
__device__ __forceinline__ float blockMaxF(float v, volatile float* sh, int lane, int wid) {
#pragma unroll
  for (int o = 32; o; o >>= 1) v = fmaxf(v, __shfl_xor(v, o));
  if (lane == 0) sh[wid] = v;
  __syncthreads();
  v = fmaxf(fmaxf(sh[0], sh[1]), fmaxf(sh[2], sh[3]));
  __syncthreads();
  return v;
}
__device__ __forceinline__ float blockSumF(float v, volatile float* sh, int lane, int wid) {
#pragma unroll
  for (int o = 32; o; o >>= 1) v += __shfl_xor(v, o);
  if (lane == 0) sh[wid] = v;
  __syncthreads();
  v = sh[0] + sh[1] + sh[2] + sh[3];
  __syncthreads();
  return v;
}
__device__ __forceinline__ int blockSumI(int v, volatile int* sh, int lane, int wid) {
#pragma unroll
  for (int o = 32; o; o >>= 1) v += __shfl_xor(v, o);
  if (lane == 0) sh[wid] = v;
  __syncthreads();
  v = sh[0] + sh[1] + sh[2] + sh[3];
  __syncthreads();
  return v;
}

// ---------------- weight transposes (so lane=o reads are coalesced) ----------------
__global__ void k_transpose(const float* __restrict__ conv_w, const float* __restrict__ gcn_w,
                            float* __restrict__ wT, float* __restrict__ gT) {
  int idx = blockIdx.x * 256 + threadIdx.x;
  if (idx < C_ * C_) {           // wT[c][o] = conv_w[o][c]
    int o = idx / C_, c = idx % C_;
    wT[c * C_ + o] = conv_w[idx];
  }
  if (idx < C_ * 2 * C_) {       // gT[i][o] = gcn_w[o][i],  i in [0,256)
    int o = idx / (2 * C_), i = idx % (2 * C_);
    gT[i * C_ + o] = gcn_w[idx];
  }
}

// ---------------- h = conv_w . x + conv_b   (lane = output channel o) ----------------
__global__ __launch_bounds__(128) void k_conv(const float* __restrict__ x,
                                              const float* __restrict__ wT,
                                              const float* __restrict__ conv_b,
                                              float* __restrict__ h) {
  const int n = blockIdx.x, b = blockIdx.y, o = threadIdx.x;
  const float* __restrict__ xb = x + (size_t)b * C_ * N_ * T_ + (size_t)n * T_;
  float acc[T_];
#pragma unroll
  for (int t = 0; t < T_; ++t) acc[t] = 0.f;
#pragma unroll 4
  for (int c = 0; c < C_; ++c) {
    float w = wT[c * C_ + o];                                   // coalesced
    const float4* xp = (const float4*)(xb + (size_t)c * N_ * T_); // wave-uniform
    float4 h0 = xp[0], h1 = xp[1], h2 = xp[2];
    FMA12(w, h0, h1, h2);
  }
  float cb = conv_b[o];
  float* __restrict__ hp = h + (((size_t)b * C_ + o) * N_ + n) * T_;
  float4 r0 = make_float4(acc[0] + cb, acc[1] + cb, acc[2] + cb, acc[3] + cb);
  float4 r1 = make_float4(acc[4] + cb, acc[5] + cb, acc[6] + cb, acc[7] + cb);
  float4 r2 = make_float4(acc[8] + cb, acc[9] + cb, acc[10] + cb, acc[11] + cb);
  ((float4*)hp)[0] = r0; ((float4*)hp)[1] = r1; ((float4*)hp)[2] = r2;
}

// ---------------- xs[b][c][n] = sum_t h[b][c][n][t]  (coalesced) ----------------
__global__ void k_xs(const float* __restrict__ h, float* __restrict__ xs) {
  int idx = blockIdx.x * 256 + threadIdx.x;
  if (idx >= B_ * C_ * N_) return;
  const float4* p = (const float4*)(h + (size_t)idx * T_);
  float4 a = p[0], b = p[1], c = p[2];
  xs[idx] = (a.x + a.y + a.z + a.w) + (b.x + b.y + b.z + b.w) + (c.x + c.y + c.z + c.w);
}

// ---------------- S1 = relu(scale*xs^T.mem), S2 = relu(scale*xs^T.xs) ----------------
// block tile: 16 n  x 256 m;  lane = m
__global__ __launch_bounds__(256) void k_scores(const float* __restrict__ xs,
                                                const float* __restrict__ mem,
                                                float* __restrict__ S1,
                                                float* __restrict__ S2) {
  const int m = blockIdx.x * 256 + threadIdx.x;
  const int n0 = blockIdx.y * 16;
  const int b = blockIdx.z;
  const bool vm = (m < N_);
  const int mc = vm ? m : 0;
  const float* __restrict__ xsb = xs + (size_t)b * C_ * N_;
  float acc1[16], acc2[16];
#pragma unroll
  for (int i = 0; i < 16; ++i) { acc1[i] = 0.f; acc2[i] = 0.f; }
  for (int c = 0; c < C_; ++c) {
    float mv = mem[(size_t)c * N_ + mc];      // coalesced
    float xv = xsb[(size_t)c * N_ + mc];      // coalesced
    const float* __restrict__ vp = xsb + (size_t)c * N_ + n0;  // wave-uniform
#pragma unroll
    for (int i = 0; i < 16; ++i) {
      float vn = vp[i];
      acc1[i] += vn * mv;
      acc2[i] += vn * xv;
    }
  }
  if (!vm) return;
#pragma unroll
  for (int i = 0; i < 16; ++i) {
    int n = n0 + i;
    if (n < N_) {
      size_t off = ((size_t)b * N_ + n) * N_ + m;
      S1[off] = fmaxf(acc1[i] * SCALE_, 0.f);
      S2[off] = fmaxf(acc2[i] * SCALE_, 0.f);
    }
  }
}

// ---------------- per-(b,n) row: softmax(S1), softmax(S2), fc, softmax, topk-mask ----------------
__global__ __launch_bounds__(256) void k_adj(const float* __restrict__ S1,
                                             const float* __restrict__ S2,
                                             const float* __restrict__ fc_w,
                                             const float* __restrict__ fc_b,
                                             float* __restrict__ adj) {
  const int n = blockIdx.x, b = blockIdx.y;
  const int tid = threadIdx.x, lane = tid & 63, wid = tid >> 6;
  __shared__ float shf[4];
  __shared__ int shi[4];
  const size_t roff = ((size_t)b * N_ + n) * N_;

  float v1[4], v2[4];
  bool val[4];
#pragma unroll
  for (int j = 0; j < 4; ++j) {
    int m = j * 256 + tid;
    val[j] = (m < N_);
    int mc = val[j] ? m : 0;
    v1[j] = S1[roff + mc];
    v2[j] = S2[roff + mc];
  }
  // softmax over v1
  float mx = -FLT_MAX;
#pragma unroll
  for (int j = 0; j < 4; ++j) if (val[j]) mx = fmaxf(mx, v1[j]);
  mx = blockMaxF(mx, shf, lane, wid);
  float sm = 0.f;
#pragma unroll
  for (int j = 0; j < 4; ++j) { float e = val[j] ? __expf(v1[j] - mx) : 0.f; v1[j] = e; sm += e; }
  sm = blockSumF(sm, shf, lane, wid);
  const float inv1 = 1.f / sm;
  // softmax over v2
  mx = -FLT_MAX;
#pragma unroll
  for (int j = 0; j < 4; ++j) if (val[j]) mx = fmaxf(mx, v2[j]);
  mx = blockMaxF(mx, shf, lane, wid);
  sm = 0.f;
#pragma unroll
  for (int j = 0; j < 4; ++j) { float e = val[j] ? __expf(v2[j] - mx) : 0.f; v2[j] = e; sm += e; }
  sm = blockSumF(sm, shf, lane, wid);
  const float inv2 = 1.f / sm;
  // fc combine -> f (stored in v1)
  const float w0 = fc_w[0], w1 = fc_w[1], fb = fc_b[0];
#pragma unroll
  for (int j = 0; j < 4; ++j) v1[j] = w0 * (v1[j] * inv1) + w1 * (v2[j] * inv2) + fb;
  // softmax over f
  mx = -FLT_MAX;
#pragma unroll
  for (int j = 0; j < 4; ++j) if (val[j]) mx = fmaxf(mx, v1[j]);
  mx = blockMaxF(mx, shf, lane, wid);
  sm = 0.f;
#pragma unroll
  for (int j = 0; j < 4; ++j) { float e = val[j] ? __expf(v1[j] - mx) : 0.f; v1[j] = e; sm += e; }
  sm = blockSumF(sm, shf, lane, wid);
  const float inv3 = 1.f / sm;

  // top-K selection on exp values (positive floats: uint order == float order)
  unsigned ui[4];
#pragma unroll
  for (int j = 0; j < 4; ++j) ui[j] = val[j] ? __float_as_uint(v1[j]) : 0u;
  unsigned lo = 0u;
  for (int bit = 30; bit >= 0; --bit) {
    unsigned cand = lo | (1u << bit);
    int lc = 0;
#pragma unroll
    for (int j = 0; j < 4; ++j) lc += (ui[j] >= cand) ? 1 : 0;  // invalid have ui=0 < cand
    int cnt = blockSumI(lc, shi, lane, wid);
    if (cnt >= K_) lo = cand;
  }
  // lo = K-th largest value's bits
  int gl = 0;
#pragma unroll
  for (int j = 0; j < 4; ++j) gl += (ui[j] > lo) ? 1 : 0;
  const int G = blockSumI(gl, shi, lane, wid);
  const int take = K_ - G;  // how many ties (== lo) to keep, by smallest index

  int base = 0;
  for (int j = 0; j < 4; ++j) {
    bool eq = val[j] && (ui[j] == lo);
    unsigned long long ball = __ballot(eq ? 1 : 0);
    if (lane == 0) shi[wid] = __popcll(ball);
    __syncthreads();
    int wpre = 0, tot = 0;
#pragma unroll
    for (int w = 0; w < 4; ++w) { int cw = shi[w]; if (w < wid) wpre += cw; tot += cw; }
    __syncthreads();
    int lpre = __builtin_amdgcn_mbcnt_hi((unsigned)(ball >> 32),
                                         __builtin_amdgcn_mbcnt_lo((unsigned)ball, 0u));
    int rank = base + wpre + lpre;
    bool keep = val[j] && ((ui[j] > lo) || (eq && rank < take));
    int m = j * 256 + tid;
    if (val[j]) adj[roff + m] = keep ? v1[j] * inv3 : 0.f;
    base += tot;
  }
}

// ---------------- gout[b,c,m,:] = sum_n gin[b,c,n,:] * adj[b,n,m]  (lane = m) ----------------
__global__ __launch_bounds__(256) void k_diff(const float* __restrict__ gin,
                                              const float* __restrict__ adj,
                                              float* __restrict__ gout) {
  const int m = blockIdx.x * 256 + threadIdx.x;
  const int c = blockIdx.y, b = blockIdx.z;
  if (m >= N_) return;
  const float* __restrict__ arow = adj + (size_t)b * N_ * N_ + m;
  const float* __restrict__ grow = gin + ((size_t)b * C_ + c) * (size_t)(N_ * T_);
  float acc[T_];
#pragma unroll
  for (int t = 0; t < T_; ++t) acc[t] = 0.f;
#pragma unroll 2
  for (int n = 0; n < N_; ++n) {
    float a = arow[(size_t)n * N_];                    // coalesced (m contiguous)
    const float4* hp = (const float4*)(grow + n * T_); // wave-uniform scalar loads
    float4 h0 = hp[0], h1 = hp[1], h2 = hp[2];
    FMA12(a, h0, h1, h2);
  }
  float* __restrict__ op = gout + (((size_t)b * C_ + c) * N_ + m) * T_;
  ((float4*)op)[0] = make_float4(acc[0], acc[1], acc[2], acc[3]);
  ((float4*)op)[1] = make_float4(acc[4], acc[5], acc[6], acc[7]);
  ((float4*)op)[2] = make_float4(acc[8], acc[9], acc[10], acc[11]);
}

// ---------------- out = (gcn_w.[g1;g2] + gcn_b)*emb + x   (lane = o) ----------------
__global__ __launch_bounds__(128) void k_out(const float* __restrict__ g1,
                                             const float* __restrict__ g2,
                                             const float* __restrict__ gT,
                                             const float* __restrict__ gcn_b,
                                             const float* __restrict__ emb,
                                             const float* __restrict__ x,
                                             float* __restrict__ out) {
  const int n = blockIdx.x, b = blockIdx.y, o = threadIdx.x;
  float acc[T_];
#pragma unroll
  for (int t = 0; t < T_; ++t) acc[t] = 0.f;
  const float* __restrict__ g1b = g1 + (size_t)b * C_ * N_ * T_ + (size_t)n * T_;
  const float* __restrict__ g2b = g2 + (size_t)b * C_ * N_ * T_ + (size_t)n * T_;
#pragma unroll 4
  for (int i = 0; i < C_; ++i) {
    float w = gT[i * C_ + o];                                    // coalesced
    const float4* gp = (const float4*)(g1b + (size_t)i * N_ * T_); // uniform
    float4 h0 = gp[0], h1 = gp[1], h2 = gp[2];
    FMA12(w, h0, h1, h2);
  }
#pragma unroll 4
  for (int i = 0; i < C_; ++i) {
    float w = gT[(C_ + i) * C_ + o];
    const float4* gp = (const float4*)(g2b + (size_t)i * N_ * T_);
    float4 h0 = gp[0], h1 = gp[1], h2 = gp[2];
    FMA12(w, h0, h1, h2);
  }
  const float eo = emb[o], gb = gcn_b[o];
  const size_t off = (((size_t)b * C_ + o) * N_ + n) * T_;
  const float4* xp = (const float4*)(x + off);
  float4 xv0 = xp[0], xv1 = xp[1], xv2 = xp[2];
  float* __restrict__ op = out + off;
  ((float4*)op)[0] = make_float4((acc[0] + gb) * eo + xv0.x, (acc[1] + gb) * eo + xv0.y,
                                 (acc[2] + gb) * eo + xv0.z, (acc[3] + gb) * eo + xv0.w);
  ((float4*)op)[1] = make_float4((acc[4] + gb) * eo + xv1.x, (acc[5] + gb) * eo + xv1.y,
                                 (acc[6] + gb) * eo + xv1.z, (acc[7] + gb) * eo + xv1.w);
  ((float4*)op)[2] = make_float4((acc[8] + gb) * eo + xv2.x, (acc[9] + gb) * eo + xv2.y,
                                 (acc[10] + gb) * eo + xv2.z, (acc[11] + gb) * eo + xv2.w);
}

extern "C" void kernel_launch(void* const* d_in, const int* in_sizes, int n_in,
                              void* d_out, int out_size, void* d_ws, size_t ws_size,
                              hipStream_t stream) {
  const float* x      = (const float*)d_in[0];
  const float* conv_w = (const float*)d_in[1];
  const float* conv_b = (const float*)d_in[2];
  const float* memory = (const float*)d_in[3];
  const float* fc_w   = (const float*)d_in[4];
  const float* fc_b   = (const float*)d_in[5];
  const float* gcn_w  = (const float*)d_in[6];
  const float* gcn_b  = (const float*)d_in[7];
  const float* emb    = (const float*)d_in[8];
  float* out = (float*)d_out;
  float* ws = (float*)d_ws;

  // workspace layout (floats). g1 overwrites S1+S2 (dead after k_adj);
  // g2 overwrites h (dead after first k_diff). Peak = 487.7 MB.
  const size_t SZ_H  = (size_t)B_ * C_ * N_ * T_;   // 43,401,216
  const size_t SZ_XS = (size_t)B_ * C_ * N_;        //  3,616,768
  const size_t SZ_S  = (size_t)B_ * N_ * N_;        // 24,952,448
  float* h   = ws;
  float* xs  = h + SZ_H;
  float* S1  = xs + SZ_XS;
  float* S2  = S1 + SZ_S;
  float* adj = S2 + SZ_S;
  float* wT  = adj + SZ_S;
  float* gT  = wT + C_ * C_;
  float* g1  = S1;   // 43.4M <= 49.9M (S1+S2)
  float* g2  = h;

  k_transpose<<<dim3(128), dim3(256), 0, stream>>>(conv_w, gcn_w, wT, gT);
  k_conv<<<dim3(N_, B_), dim3(128), 0, stream>>>(x, wT, conv_b, h);
  k_xs<<<dim3((B_ * C_ * N_ + 255) / 256), dim3(256), 0, stream>>>(h, xs);
  k_scores<<<dim3(4, 56, B_), dim3(256), 0, stream>>>(xs, memory, S1, S2);
  k_adj<<<dim3(N_, B_), dim3(256), 0, stream>>>(S1, S2, fc_w, fc_b, adj);
  k_diff<<<dim3(4, C_, B_), dim3(256), 0, stream>>>(h, adj, g1);
  k_diff<<<dim3(4, C_, B_), dim3(256), 0, stream>>>(g1, adj, g2);
  k_out<<<dim3(N_, B_), dim3(128), 0, stream>>>(g1, g2, gT, gcn_b, emb, x, out);
}

// Round 2
// 3119.606 us; speedup vs baseline: 2.4303x; 2.4303x over previous
//
#include <hip/hip_runtime.h>
#include <hip/hip_bf16.h>
#include <float.h>

#define B_ 32
#define C_ 128
#define N_ 883
#define T_ 12
#define K_ 706        // int(883*0.8)
#define NP_ 896       // N padded to multiple of 32 (K/N pad for GEMM)
#define R_ 1536       // C_*T_
#define SCALE_ 0.08838834764831845f  // 1/sqrt(128)

typedef unsigned short ushortT;
typedef float f32x4 __attribute__((ext_vector_type(4)));
typedef __bf16 bf16x8 __attribute__((ext_vector_type(8)));

__device__ __forceinline__ ushortT f2bf(float f) {
  union { __hip_bfloat16 h; ushortT u; } cv; cv.h = __float2bfloat16(f); return cv.u;
}
__device__ __forceinline__ float bf2f(ushortT u) {
  union { __hip_bfloat16 h; ushortT u; } cv; cv.u = u; return __bfloat162float(cv.h);
}

// 12-wide FMA into acc[] from three float4 loads
#define FMA12(a, h0, h1, h2) \
  acc[0] += (a)*(h0).x; acc[1] += (a)*(h0).y; acc[2] += (a)*(h0).z; acc[3] += (a)*(h0).w; \
  acc[4] += (a)*(h1).x; acc[5] += (a)*(h1).y; acc[6] += (a)*(h1).z; acc[7] += (a)*(h1).w; \
  acc[8] += (a)*(h2).x; acc[9] += (a)*(h2).y; acc[10] += (a)*(h2).z; acc[11] += (a)*(h2).w;

// ---------------- block reduction helpers (256 threads = 4 waves) ----------------
__device__ __forceinline__ float blockMaxF(float v, volatile float* sh, int lane, int wid) {
#pragma unroll
  for (int o = 32; o; o >>= 1) v = fmaxf(v, __shfl_xor(v, o));
  if (lane == 0) sh[wid] = v;
  __syncthreads();
  v = fmaxf(fmaxf(sh[0], sh[1]), fmaxf(sh[2], sh[3]));
  __syncthreads();
  return v;
}
__device__ __forceinline__ float blockSumF(float v, volatile float* sh, int lane, int wid) {
#pragma unroll
  for (int o = 32; o; o >>= 1) v += __shfl_xor(v, o);
  if (lane == 0) sh[wid] = v;
  __syncthreads();
  v = sh[0] + sh[1] + sh[2] + sh[3];
  __syncthreads();
  return v;
}
__device__ __forceinline__ int blockSumI(int v, volatile int* sh, int lane, int wid) {
#pragma unroll
  for (int o = 32; o; o >>= 1) v += __shfl_xor(v, o);
  if (lane == 0) sh[wid] = v;
  __syncthreads();
  v = sh[0] + sh[1] + sh[2] + sh[3];
  __syncthreads();
  return v;
}

// ---------------- weight transposes ----------------
__global__ void k_transpose(const float* __restrict__ conv_w, const float* __restrict__ gcn_w,
                            float* __restrict__ wT, float* __restrict__ gT) {
  int idx = blockIdx.x * 256 + threadIdx.x;
  if (idx < C_ * C_) {           // wT[c][o] = conv_w[o][c]
    int o = idx / C_, c = idx % C_;
    wT[c * C_ + o] = conv_w[idx];
  }
  if (idx < C_ * 2 * C_) {       // gT[i][o] = gcn_w[o][i],  i in [0,256)
    int o = idx / (2 * C_), i = idx % (2 * C_);
    gT[i * C_ + o] = gcn_w[idx];
  }
}

// ---------------- h = conv_w . x + conv_b   (lane = output channel o) ----------------
__global__ __launch_bounds__(128) void k_conv(const float* __restrict__ x,
                                              const float* __restrict__ wT,
                                              const float* __restrict__ conv_b,
                                              float* __restrict__ h) {
  const int n = blockIdx.x, b = blockIdx.y, o = threadIdx.x;
  const float* __restrict__ xb = x + (size_t)b * C_ * N_ * T_ + (size_t)n * T_;
  float acc[T_];
#pragma unroll
  for (int t = 0; t < T_; ++t) acc[t] = 0.f;
#pragma unroll 4
  for (int c = 0; c < C_; ++c) {
    float w = wT[c * C_ + o];                                     // coalesced
    const float4* xp = (const float4*)(xb + (size_t)c * N_ * T_); // wave-uniform
    float4 h0 = xp[0], h1 = xp[1], h2 = xp[2];
    FMA12(w, h0, h1, h2);
  }
  float cb = conv_b[o];
  float* __restrict__ hp = h + (((size_t)b * C_ + o) * N_ + n) * T_;
  ((float4*)hp)[0] = make_float4(acc[0] + cb, acc[1] + cb, acc[2] + cb, acc[3] + cb);
  ((float4*)hp)[1] = make_float4(acc[4] + cb, acc[5] + cb, acc[6] + cb, acc[7] + cb);
  ((float4*)hp)[2] = make_float4(acc[8] + cb, acc[9] + cb, acc[10] + cb, acc[11] + cb);
}

// ---------------- xs[b][c][n] = sum_t h[b][c][n][t] ----------------
__global__ void k_xs(const float* __restrict__ h, float* __restrict__ xs) {
  int idx = blockIdx.x * 256 + threadIdx.x;
  if (idx >= B_ * C_ * N_) return;
  const float4* p = (const float4*)(h + (size_t)idx * T_);
  float4 a = p[0], b = p[1], c = p[2];
  xs[idx] = (a.x + a.y + a.z + a.w) + (b.x + b.y + b.z + b.w) + (c.x + c.y + c.z + c.w);
}

// ---------------- hb[b][(c,t)][n] = bf16(h[b][c][n][t]), n padded to 896 w/ zeros --------
__global__ __launch_bounds__(256) void k_hb(const float* __restrict__ h,
                                            ushortT* __restrict__ hb) {
  const int c = blockIdx.x, b = blockIdx.y, tid = threadIdx.x;
  __shared__ ushortT lt[T_ * NP_];  // 21 KB
  const float* __restrict__ hp = h + ((size_t)(b * C_ + c)) * (N_ * T_);
  for (int j = tid; j < N_ * T_; j += 256) {
    int n = j / T_, t = j - n * T_;              // coalesced read of h
    lt[t * NP_ + n] = f2bf(hp[j]);
  }
  __syncthreads();
  ushortT* __restrict__ ob = hb + ((size_t)b * R_ + c * T_) * NP_;
  for (int j = tid; j < T_ * NP_; j += 256) {
    int n = j % NP_;
    ob[j] = (n < N_) ? lt[j] : (ushortT)0;       // zero the K-pad
  }
}

// ---------------- S1 = relu(scale*xs^T.mem), S2 = relu(scale*xs^T.xs), bf16 out ---------
__global__ __launch_bounds__(256) void k_scores(const float* __restrict__ xs,
                                                const float* __restrict__ mem,
                                                ushortT* __restrict__ S1,
                                                ushortT* __restrict__ S2) {
  const int m = blockIdx.x * 256 + threadIdx.x;
  const int n0 = blockIdx.y * 16;
  const int b = blockIdx.z;
  const bool vm = (m < N_);
  const int mc = vm ? m : 0;
  const float* __restrict__ xsb = xs + (size_t)b * C_ * N_;
  float acc1[16], acc2[16];
#pragma unroll
  for (int i = 0; i < 16; ++i) { acc1[i] = 0.f; acc2[i] = 0.f; }
  for (int c = 0; c < C_; ++c) {
    float mv = mem[(size_t)c * N_ + mc];
    float xv = xsb[(size_t)c * N_ + mc];
    const float* __restrict__ vp = xsb + (size_t)c * N_ + n0;
#pragma unroll
    for (int i = 0; i < 16; ++i) {
      float vn = vp[i];
      acc1[i] += vn * mv;
      acc2[i] += vn * xv;
    }
  }
  if (!vm) return;
#pragma unroll
  for (int i = 0; i < 16; ++i) {
    int n = n0 + i;
    if (n < N_) {
      size_t off = ((size_t)b * N_ + n) * N_ + m;
      S1[off] = f2bf(fmaxf(acc1[i] * SCALE_, 0.f));
      S2[off] = f2bf(fmaxf(acc2[i] * SCALE_, 0.f));
    }
  }
}

// ---------------- per-(b,n) row: softmaxes, fc, softmax, topk -> adjT bf16 ----------------
__global__ __launch_bounds__(256) void k_adj(const ushortT* __restrict__ S1,
                                             const ushortT* __restrict__ S2,
                                             const float* __restrict__ fc_w,
                                             const float* __restrict__ fc_b,
                                             ushortT* __restrict__ adjT) {
  const int n = blockIdx.x, b = blockIdx.y;
  const int tid = threadIdx.x, lane = tid & 63, wid = tid >> 6;
  __shared__ float shf[4];
  __shared__ int shi[4];
  const size_t roff = ((size_t)b * N_ + n) * N_;

  float v1[4], v2[4];
  bool val[4];
#pragma unroll
  for (int j = 0; j < 4; ++j) {
    int m = j * 256 + tid;
    val[j] = (m < N_);
    int mc = val[j] ? m : 0;
    v1[j] = bf2f(S1[roff + mc]);
    v2[j] = bf2f(S2[roff + mc]);
  }
  float mx = -FLT_MAX;
#pragma unroll
  for (int j = 0; j < 4; ++j) if (val[j]) mx = fmaxf(mx, v1[j]);
  mx = blockMaxF(mx, shf, lane, wid);
  float sm = 0.f;
#pragma unroll
  for (int j = 0; j < 4; ++j) { float e = val[j] ? __expf(v1[j] - mx) : 0.f; v1[j] = e; sm += e; }
  sm = blockSumF(sm, shf, lane, wid);
  const float inv1 = 1.f / sm;
  mx = -FLT_MAX;
#pragma unroll
  for (int j = 0; j < 4; ++j) if (val[j]) mx = fmaxf(mx, v2[j]);
  mx = blockMaxF(mx, shf, lane, wid);
  sm = 0.f;
#pragma unroll
  for (int j = 0; j < 4; ++j) { float e = val[j] ? __expf(v2[j] - mx) : 0.f; v2[j] = e; sm += e; }
  sm = blockSumF(sm, shf, lane, wid);
  const float inv2 = 1.f / sm;
  const float w0 = fc_w[0], w1 = fc_w[1], fb = fc_b[0];
#pragma unroll
  for (int j = 0; j < 4; ++j) v1[j] = w0 * (v1[j] * inv1) + w1 * (v2[j] * inv2) + fb;
  mx = -FLT_MAX;
#pragma unroll
  for (int j = 0; j < 4; ++j) if (val[j]) mx = fmaxf(mx, v1[j]);
  mx = blockMaxF(mx, shf, lane, wid);
  sm = 0.f;
#pragma unroll
  for (int j = 0; j < 4; ++j) { float e = val[j] ? __expf(v1[j] - mx) : 0.f; v1[j] = e; sm += e; }
  sm = blockSumF(sm, shf, lane, wid);
  const float inv3 = 1.f / sm;

  unsigned ui[4];
#pragma unroll
  for (int j = 0; j < 4; ++j) ui[j] = val[j] ? __float_as_uint(v1[j]) : 0u;
  unsigned lo = 0u;
  for (int bit = 30; bit >= 0; --bit) {
    unsigned cand = lo | (1u << bit);
    int lc = 0;
#pragma unroll
    for (int j = 0; j < 4; ++j) lc += (ui[j] >= cand) ? 1 : 0;
    int cnt = blockSumI(lc, shi, lane, wid);
    if (cnt >= K_) lo = cand;
  }
  int gl = 0;
#pragma unroll
  for (int j = 0; j < 4; ++j) gl += (ui[j] > lo) ? 1 : 0;
  const int G = blockSumI(gl, shi, lane, wid);
  const int take = K_ - G;  // ties kept by smallest index (lax.top_k stability)

  ushortT* __restrict__ aT = adjT + (size_t)b * NP_ * NP_;
  int base = 0;
  for (int j = 0; j < 4; ++j) {
    bool eq = val[j] && (ui[j] == lo);
    unsigned long long ball = __ballot(eq ? 1 : 0);
    if (lane == 0) shi[wid] = __popcll(ball);
    __syncthreads();
    int wpre = 0, tot = 0;
#pragma unroll
    for (int w = 0; w < 4; ++w) { int cw = shi[w]; if (w < wid) wpre += cw; tot += cw; }
    __syncthreads();
    int lpre = __builtin_amdgcn_mbcnt_hi((unsigned)(ball >> 32),
                                         __builtin_amdgcn_mbcnt_lo((unsigned)ball, 0u));
    int rank = base + wpre + lpre;
    bool keep = val[j] && ((ui[j] > lo) || (eq && rank < take));
    int m = j * 256 + tid;
    if (val[j]) aT[(size_t)m * NP_ + n] = keep ? f2bf(v1[j] * inv3) : (ushortT)0;
    base += tot;
  }
}

// ---------------- MFMA GEMM: D[r][m] = sum_k A[r][k]*adj[k][m], bf16 in/out ----------------
#define GLOAD16(gp, lp) __builtin_amdgcn_global_load_lds( \
    (const __attribute__((address_space(1))) unsigned int*)(gp), \
    (__attribute__((address_space(3))) unsigned int*)(lp), 16, 0, 0)

// bijective 16B-unit swizzle: rows spread across bank-quads (2-way = free)
__device__ __forceinline__ int frag_u(int row, int kg) {
  int bu = row >> 1;
  int inner = ((row & 1) << 2) | kg;
  return (bu << 3) | (inner ^ (bu & 7));
}

__device__ __forceinline__ void stage_tile(const ushortT* __restrict__ gbase, int row0, int k0,
                                           ushortT* lds, int w, int l) {
#pragma unroll
  for (int i = 0; i < 2; ++i) {
    int u = w * 128 + i * 64 + l;
    int bu = u >> 3;
    int inner = (u & 7) ^ (bu & 7);
    int row = bu * 2 + (inner >> 2);
    int kg = inner & 3;
    const ushortT* src = gbase + (size_t)(row0 + row) * NP_ + k0 + kg * 8;
    GLOAD16(src, lds + u * 8);
  }
}

__global__ __launch_bounds__(256) void k_diffm(const ushortT* __restrict__ A,
                                               const ushortT* __restrict__ Bt,
                                               ushortT* __restrict__ D) {
  __shared__ ushortT ldsA[2][4096], ldsB[2][4096];  // 32 KB
  const int tid = threadIdx.x, l = tid & 63, w = tid >> 6;
  const int wr = w >> 1, wc = w & 1;
  const int m0 = blockIdx.x * 128, r0 = blockIdx.y * 128;
  const size_t boffA = (size_t)blockIdx.z * R_ * NP_;
  const size_t boffB = (size_t)blockIdx.z * NP_ * NP_;
  const ushortT* __restrict__ Ab = A + boffA;
  const ushortT* __restrict__ Bb = Bt + boffB;

  f32x4 acc[4][4];
#pragma unroll
  for (int i = 0; i < 4; ++i)
#pragma unroll
    for (int j = 0; j < 4; ++j) acc[i][j] = f32x4{0.f, 0.f, 0.f, 0.f};

  stage_tile(Ab, r0, 0, &ldsA[0][0], w, l);
  stage_tile(Bb, m0, 0, &ldsB[0][0], w, l);
  asm volatile("s_waitcnt vmcnt(0)" ::: "memory");
  __syncthreads();

  const int kg = l >> 4, rl = l & 15;
  for (int kt = 0; kt < 28; ++kt) {
    const int pb = kt & 1;
    if (kt < 27) {
      stage_tile(Ab, r0, (kt + 1) * 32, &ldsA[pb ^ 1][0], w, l);
      stage_tile(Bb, m0, (kt + 1) * 32, &ldsB[pb ^ 1][0], w, l);
    }
    bf16x8 af[4], bfr[4];
#pragma unroll
    for (int fi = 0; fi < 4; ++fi)
      af[fi] = *(const bf16x8*)&ldsA[pb][frag_u(wr * 64 + fi * 16 + rl, kg) * 8];
#pragma unroll
    for (int fj = 0; fj < 4; ++fj)
      bfr[fj] = *(const bf16x8*)&ldsB[pb][frag_u(wc * 64 + fj * 16 + rl, kg) * 8];
#pragma unroll
    for (int fi = 0; fi < 4; ++fi)
#pragma unroll
      for (int fj = 0; fj < 4; ++fj)
        acc[fi][fj] = __builtin_amdgcn_mfma_f32_16x16x32_bf16(af[fi], bfr[fj], acc[fi][fj], 0, 0, 0);
    asm volatile("s_waitcnt vmcnt(0)" ::: "memory");
    __syncthreads();
  }

  // epilogue: C/D layout col=lane&15, row=(lane>>4)*4+reg  [m89-verified]
  ushortT* __restrict__ Db = D + boffA;
#pragma unroll
  for (int fj = 0; fj < 4; ++fj) {
    int m = m0 + wc * 64 + fj * 16 + (l & 15);
    if (m < N_) {
#pragma unroll
      for (int fi = 0; fi < 4; ++fi) {
#pragma unroll
        for (int v = 0; v < 4; ++v) {
          int r = r0 + wr * 64 + fi * 16 + (l >> 4) * 4 + v;
          Db[(size_t)r * NP_ + m] = f2bf(acc[fi][fj][v]);
        }
      }
    }
  }
}

// ---------------- out = (gcn_w.[g1;g2] + gcn_b)*emb + x  (broadcast g across o) --------
__global__ __launch_bounds__(256) void k_out(const ushortT* __restrict__ g1b,
                                             const ushortT* __restrict__ g2b,
                                             const float* __restrict__ gT,
                                             const float* __restrict__ gcn_b,
                                             const float* __restrict__ emb,
                                             const float* __restrict__ x,
                                             float* __restrict__ out) {
  const int o = threadIdx.x >> 1, half = threadIdx.x & 1;
  const int n0 = blockIdx.x * 8 + half * 4;
  const int b = blockIdx.y;
  float acc[12][4];
#pragma unroll
  for (int t = 0; t < 12; ++t)
#pragma unroll
    for (int j = 0; j < 4; ++j) acc[t][j] = 0.f;
  const ushortT* __restrict__ g1p = g1b + (size_t)b * R_ * NP_ + n0;
  const ushortT* __restrict__ g2p = g2b + (size_t)b * R_ * NP_ + n0;
  for (int c = 0; c < C_; ++c) {
    float w1 = gT[c * C_ + o];
    float w2 = gT[(C_ + c) * C_ + o];
#pragma unroll
    for (int t = 0; t < T_; ++t) {
      ushort4 u1 = *(const ushort4*)&g1p[(c * T_ + t) * NP_];
      ushort4 u2 = *(const ushort4*)&g2p[(c * T_ + t) * NP_];
      acc[t][0] += w1 * bf2f(u1.x) + w2 * bf2f(u2.x);
      acc[t][1] += w1 * bf2f(u1.y) + w2 * bf2f(u2.y);
      acc[t][2] += w1 * bf2f(u1.z) + w2 * bf2f(u2.z);
      acc[t][3] += w1 * bf2f(u1.w) + w2 * bf2f(u2.w);
    }
  }
  const float eo = emb[o], gb = gcn_b[o];
#pragma unroll
  for (int j = 0; j < 4; ++j) {
    int n = n0 + j;
    if (n < N_) {
      size_t off = (((size_t)b * C_ + o) * N_ + n) * T_;
      const float4* xp = (const float4*)&x[off];
      float4 x0 = xp[0], x1 = xp[1], x2 = xp[2];
      float* __restrict__ op = out + off;
      ((float4*)op)[0] = make_float4((acc[0][j] + gb) * eo + x0.x, (acc[1][j] + gb) * eo + x0.y,
                                     (acc[2][j] + gb) * eo + x0.z, (acc[3][j] + gb) * eo + x0.w);
      ((float4*)op)[1] = make_float4((acc[4][j] + gb) * eo + x1.x, (acc[5][j] + gb) * eo + x1.y,
                                     (acc[6][j] + gb) * eo + x1.z, (acc[7][j] + gb) * eo + x1.w);
      ((float4*)op)[2] = make_float4((acc[8][j] + gb) * eo + x2.x, (acc[9][j] + gb) * eo + x2.y,
                                     (acc[10][j] + gb) * eo + x2.z, (acc[11][j] + gb) * eo + x2.w);
    }
  }
}

extern "C" void kernel_launch(void* const* d_in, const int* in_sizes, int n_in,
                              void* d_out, int out_size, void* d_ws, size_t ws_size,
                              hipStream_t stream) {
  const float* x      = (const float*)d_in[0];
  const float* conv_w = (const float*)d_in[1];
  const float* conv_b = (const float*)d_in[2];
  const float* memory = (const float*)d_in[3];
  const float* fc_w   = (const float*)d_in[4];
  const float* fc_b   = (const float*)d_in[5];
  const float* gcn_w  = (const float*)d_in[6];
  const float* gcn_b  = (const float*)d_in[7];
  const float* emb    = (const float*)d_in[8];
  float* out = (float*)d_out;

  // workspace (bytes, all 16B-aligned). g1b reuses h (dead after k_hb/k_xs);
  // g2b reuses S1b+S2b (dead after k_adj). Peak = 427.6 MB.
  char* p = (char*)d_ws;
  float*   h    = (float*)p;    p += (size_t)B_ * C_ * N_ * T_ * 4;   // 173.6 MB
  float*   xs   = (float*)p;    p += (size_t)B_ * C_ * N_ * 4;        //  14.5 MB
  ushortT* S1b  = (ushortT*)p;  p += (size_t)B_ * N_ * N_ * 2;        //  49.9 MB
  ushortT* S2b  = (ushortT*)p;  p += (size_t)B_ * N_ * N_ * 2;        //  49.9 MB
  ushortT* adjT = (ushortT*)p;  p += (size_t)B_ * NP_ * NP_ * 2;      //  51.4 MB
  ushortT* hb   = (ushortT*)p;  p += (size_t)B_ * R_ * NP_ * 2;       //  88.1 MB
  float*   wT   = (float*)p;    p += C_ * C_ * 4;
  float*   gT   = (float*)p;    p += 2 * C_ * C_ * 4;
  ushortT* g1b  = (ushortT*)h;
  ushortT* g2b  = (ushortT*)S1b;

  k_transpose<<<dim3(128), dim3(256), 0, stream>>>(conv_w, gcn_w, wT, gT);
  k_conv<<<dim3(N_, B_), dim3(128), 0, stream>>>(x, wT, conv_b, h);
  k_xs<<<dim3((B_ * C_ * N_ + 255) / 256), dim3(256), 0, stream>>>(h, xs);
  k_hb<<<dim3(C_, B_), dim3(256), 0, stream>>>(h, hb);
  hipMemsetAsync(g1b, 0, (size_t)B_ * R_ * NP_ * 2, stream);  // zero K-pad cols for GEMM2
  k_scores<<<dim3(4, 56, B_), dim3(256), 0, stream>>>(xs, memory, S1b, S2b);
  k_adj<<<dim3(N_, B_), dim3(256), 0, stream>>>(S1b, S2b, fc_w, fc_b, adjT);
  k_diffm<<<dim3(7, 12, B_), dim3(256), 0, stream>>>(hb, adjT, g1b);
  k_diffm<<<dim3(7, 12, B_), dim3(256), 0, stream>>>(g1b, adjT, g2b);
  k_out<<<dim3(111, B_), dim3(256), 0, stream>>>(g1b, g2b, gT, gcn_b, emb, x, out);
}

// Round 3
// 2347.897 us; speedup vs baseline: 3.2291x; 1.3287x over previous
//
#include <hip/hip_runtime.h>
#include <hip/hip_bf16.h>
#include <float.h>

#define B_ 32
#define C_ 128
#define N_ 883
#define T_ 12
#define K_ 706        // int(883*0.8)
#define NP_ 896       // N padded to multiple of 32
#define R_ 1536       // C_*T_
#define KI_ 256       // k_out contraction size (2*C_)
#define SCALE_ 0.08838834764831845f  // 1/sqrt(128)

typedef unsigned short ushortT;
typedef float f32x4 __attribute__((ext_vector_type(4)));
typedef __bf16 bf16x8 __attribute__((ext_vector_type(8)));

__device__ __forceinline__ ushortT f2bf(float f) {
  union { __hip_bfloat16 h; ushortT u; } cv; cv.h = __float2bfloat16(f); return cv.u;
}
__device__ __forceinline__ float bf2f(ushortT u) {
  union { __hip_bfloat16 h; ushortT u; } cv; cv.u = u; return __bfloat162float(cv.h);
}

// 12-wide FMA into acc[] from three float4 loads
#define FMA12(a, h0, h1, h2) \
  acc[0] += (a)*(h0).x; acc[1] += (a)*(h0).y; acc[2] += (a)*(h0).z; acc[3] += (a)*(h0).w; \
  acc[4] += (a)*(h1).x; acc[5] += (a)*(h1).y; acc[6] += (a)*(h1).z; acc[7] += (a)*(h1).w; \
  acc[8] += (a)*(h2).x; acc[9] += (a)*(h2).y; acc[10] += (a)*(h2).z; acc[11] += (a)*(h2).w;

// ---------------- block reduction helpers (256 threads = 4 waves) ----------------
__device__ __forceinline__ float blockMaxF(float v, volatile float* sh, int lane, int wid) {
#pragma unroll
  for (int o = 32; o; o >>= 1) v = fmaxf(v, __shfl_xor(v, o));
  if (lane == 0) sh[wid] = v;
  __syncthreads();
  v = fmaxf(fmaxf(sh[0], sh[1]), fmaxf(sh[2], sh[3]));
  __syncthreads();
  return v;
}
__device__ __forceinline__ float blockSumF(float v, volatile float* sh, int lane, int wid) {
#pragma unroll
  for (int o = 32; o; o >>= 1) v += __shfl_xor(v, o);
  if (lane == 0) sh[wid] = v;
  __syncthreads();
  v = sh[0] + sh[1] + sh[2] + sh[3];
  __syncthreads();
  return v;
}
__device__ __forceinline__ int blockSumI(int v, volatile int* sh, int lane, int wid) {
#pragma unroll
  for (int o = 32; o; o >>= 1) v += __shfl_xor(v, o);
  if (lane == 0) sh[wid] = v;
  __syncthreads();
  v = sh[0] + sh[1] + sh[2] + sh[3];
  __syncthreads();
  return v;
}

// ---------------- weight prep: wT (fp32 transpose), gcn_wb (bf16 copy) ----------------
__global__ void k_transpose(const float* __restrict__ conv_w, const float* __restrict__ gcn_w,
                            float* __restrict__ wT, ushortT* __restrict__ gcn_wb) {
  int idx = blockIdx.x * 256 + threadIdx.x;
  if (idx < C_ * C_) {           // wT[c][o] = conv_w[o][c]
    int o = idx / C_, c = idx % C_;
    wT[c * C_ + o] = conv_w[idx];
  }
  if (idx < C_ * KI_) {          // gcn_wb[o][i] = bf16(gcn_w[o][i])
    gcn_wb[idx] = f2bf(gcn_w[idx]);
  }
}

// ---------------- h = conv_w . x + conv_b   (lane = output channel o) ----------------
__global__ __launch_bounds__(128) void k_conv(const float* __restrict__ x,
                                              const float* __restrict__ wT,
                                              const float* __restrict__ conv_b,
                                              float* __restrict__ h) {
  const int n = blockIdx.x, b = blockIdx.y, o = threadIdx.x;
  const float* __restrict__ xb = x + (size_t)b * C_ * N_ * T_ + (size_t)n * T_;
  float acc[T_];
#pragma unroll
  for (int t = 0; t < T_; ++t) acc[t] = 0.f;
#pragma unroll 4
  for (int c = 0; c < C_; ++c) {
    float w = wT[c * C_ + o];                                     // coalesced
    const float4* xp = (const float4*)(xb + (size_t)c * N_ * T_); // wave-uniform
    float4 h0 = xp[0], h1 = xp[1], h2 = xp[2];
    FMA12(w, h0, h1, h2);
  }
  float cb = conv_b[o];
  float* __restrict__ hp = h + (((size_t)b * C_ + o) * N_ + n) * T_;
  ((float4*)hp)[0] = make_float4(acc[0] + cb, acc[1] + cb, acc[2] + cb, acc[3] + cb);
  ((float4*)hp)[1] = make_float4(acc[4] + cb, acc[5] + cb, acc[6] + cb, acc[7] + cb);
  ((float4*)hp)[2] = make_float4(acc[8] + cb, acc[9] + cb, acc[10] + cb, acc[11] + cb);
}

// ---------------- xs[b][c][n] = sum_t h[b][c][n][t] ----------------
__global__ void k_xs(const float* __restrict__ h, float* __restrict__ xs) {
  int idx = blockIdx.x * 256 + threadIdx.x;
  if (idx >= B_ * C_ * N_) return;
  const float4* p = (const float4*)(h + (size_t)idx * T_);
  float4 a = p[0], b = p[1], c = p[2];
  xs[idx] = (a.x + a.y + a.z + a.w) + (b.x + b.y + b.z + b.w) + (c.x + c.y + c.z + c.w);
}

// ------- hb[b][t*128+c][n] = bf16(h[b][c][n][t]), rows (t,c), n padded w/ zeros -------
__global__ __launch_bounds__(256) void k_hb(const float* __restrict__ h,
                                            ushortT* __restrict__ hb) {
  const int c = blockIdx.x, b = blockIdx.y, tid = threadIdx.x;
  __shared__ ushortT lt[T_ * NP_];  // 21 KB
  const float* __restrict__ hp = h + ((size_t)(b * C_ + c)) * (N_ * T_);
  for (int j = tid; j < N_ * T_; j += 256) {
    int n = j / T_, t = j - n * T_;              // coalesced read of h
    lt[t * NP_ + n] = f2bf(hp[j]);
  }
  __syncthreads();
  ushortT* __restrict__ ob = hb + (size_t)b * R_ * NP_;
  for (int j = tid; j < T_ * NP_; j += 256) {
    int t = j / NP_, n = j - t * NP_;
    ob[(size_t)(t * C_ + c) * NP_ + n] = (n < N_) ? lt[j] : (ushortT)0;  // zero K-pad
  }
}

// ---------------- S1 = relu(scale*xs^T.mem), S2 = relu(scale*xs^T.xs), bf16 out ---------
__global__ __launch_bounds__(256) void k_scores(const float* __restrict__ xs,
                                                const float* __restrict__ mem,
                                                ushortT* __restrict__ S1,
                                                ushortT* __restrict__ S2) {
  const int m = blockIdx.x * 256 + threadIdx.x;
  const int n0 = blockIdx.y * 16;
  const int b = blockIdx.z;
  const bool vm = (m < N_);
  const int mc = vm ? m : 0;
  const float* __restrict__ xsb = xs + (size_t)b * C_ * N_;
  float acc1[16], acc2[16];
#pragma unroll
  for (int i = 0; i < 16; ++i) { acc1[i] = 0.f; acc2[i] = 0.f; }
  for (int c = 0; c < C_; ++c) {
    float mv = mem[(size_t)c * N_ + mc];
    float xv = xsb[(size_t)c * N_ + mc];
    const float* __restrict__ vp = xsb + (size_t)c * N_ + n0;
#pragma unroll
    for (int i = 0; i < 16; ++i) {
      float vn = vp[i];
      acc1[i] += vn * mv;
      acc2[i] += vn * xv;
    }
  }
  if (!vm) return;
#pragma unroll
  for (int i = 0; i < 16; ++i) {
    int n = n0 + i;
    if (n < N_) {
      size_t off = ((size_t)b * N_ + n) * N_ + m;
      S1[off] = f2bf(fmaxf(acc1[i] * SCALE_, 0.f));
      S2[off] = f2bf(fmaxf(acc2[i] * SCALE_, 0.f));
    }
  }
}

// ---------------- per-(b,n) row: softmaxes, fc, softmax, topk -> adjT bf16 ----------------
__global__ __launch_bounds__(256) void k_adj(const ushortT* __restrict__ S1,
                                             const ushortT* __restrict__ S2,
                                             const float* __restrict__ fc_w,
                                             const float* __restrict__ fc_b,
                                             ushortT* __restrict__ adjT) {
  const int n = blockIdx.x, b = blockIdx.y;
  const int tid = threadIdx.x, lane = tid & 63, wid = tid >> 6;
  __shared__ float shf[4];
  __shared__ int shi[4];
  const size_t roff = ((size_t)b * N_ + n) * N_;

  float v1[4], v2[4];
  bool val[4];
#pragma unroll
  for (int j = 0; j < 4; ++j) {
    int m = j * 256 + tid;
    val[j] = (m < N_);
    int mc = val[j] ? m : 0;
    v1[j] = bf2f(S1[roff + mc]);
    v2[j] = bf2f(S2[roff + mc]);
  }
  float mx = -FLT_MAX;
#pragma unroll
  for (int j = 0; j < 4; ++j) if (val[j]) mx = fmaxf(mx, v1[j]);
  mx = blockMaxF(mx, shf, lane, wid);
  float sm = 0.f;
#pragma unroll
  for (int j = 0; j < 4; ++j) { float e = val[j] ? __expf(v1[j] - mx) : 0.f; v1[j] = e; sm += e; }
  sm = blockSumF(sm, shf, lane, wid);
  const float inv1 = 1.f / sm;
  mx = -FLT_MAX;
#pragma unroll
  for (int j = 0; j < 4; ++j) if (val[j]) mx = fmaxf(mx, v2[j]);
  mx = blockMaxF(mx, shf, lane, wid);
  sm = 0.f;
#pragma unroll
  for (int j = 0; j < 4; ++j) { float e = val[j] ? __expf(v2[j] - mx) : 0.f; v2[j] = e; sm += e; }
  sm = blockSumF(sm, shf, lane, wid);
  const float inv2 = 1.f / sm;
  const float w0 = fc_w[0], w1 = fc_w[1], fb = fc_b[0];
#pragma unroll
  for (int j = 0; j < 4; ++j) v1[j] = w0 * (v1[j] * inv1) + w1 * (v2[j] * inv2) + fb;
  mx = -FLT_MAX;
#pragma unroll
  for (int j = 0; j < 4; ++j) if (val[j]) mx = fmaxf(mx, v1[j]);
  mx = blockMaxF(mx, shf, lane, wid);
  sm = 0.f;
#pragma unroll
  for (int j = 0; j < 4; ++j) { float e = val[j] ? __expf(v1[j] - mx) : 0.f; v1[j] = e; sm += e; }
  sm = blockSumF(sm, shf, lane, wid);
  const float inv3 = 1.f / sm;

  unsigned ui[4];
#pragma unroll
  for (int j = 0; j < 4; ++j) ui[j] = val[j] ? __float_as_uint(v1[j]) : 0u;
  unsigned lo = 0u;
  for (int bit = 30; bit >= 0; --bit) {
    unsigned cand = lo | (1u << bit);
    int lc = 0;
#pragma unroll
    for (int j = 0; j < 4; ++j) lc += (ui[j] >= cand) ? 1 : 0;
    int cnt = blockSumI(lc, shi, lane, wid);
    if (cnt >= K_) lo = cand;
  }
  int gl = 0;
#pragma unroll
  for (int j = 0; j < 4; ++j) gl += (ui[j] > lo) ? 1 : 0;
  const int G = blockSumI(gl, shi, lane, wid);
  const int take = K_ - G;  // ties kept by smallest index (lax.top_k stability)

  ushortT* __restrict__ aT = adjT + (size_t)b * NP_ * NP_;
  int base = 0;
  for (int j = 0; j < 4; ++j) {
    bool eq = val[j] && (ui[j] == lo);
    unsigned long long ball = __ballot(eq ? 1 : 0);
    if (lane == 0) shi[wid] = __popcll(ball);
    __syncthreads();
    int wpre = 0, tot = 0;
#pragma unroll
    for (int w = 0; w < 4; ++w) { int cw = shi[w]; if (w < wid) wpre += cw; tot += cw; }
    __syncthreads();
    int lpre = __builtin_amdgcn_mbcnt_hi((unsigned)(ball >> 32),
                                         __builtin_amdgcn_mbcnt_lo((unsigned)ball, 0u));
    int rank = base + wpre + lpre;
    bool keep = val[j] && ((ui[j] > lo) || (eq && rank < take));
    int m = j * 256 + tid;
    if (val[j]) aT[(size_t)m * NP_ + n] = keep ? f2bf(v1[j] * inv3) : (ushortT)0;
    base += tot;
  }
}

// ---------------- shared MFMA GEMM machinery ----------------
#define GLOAD16(gp, lp) __builtin_amdgcn_global_load_lds( \
    (const __attribute__((address_space(1))) unsigned int*)(gp), \
    (__attribute__((address_space(3))) unsigned int*)(lp), 16, 0, 0)

// bijective 16B-unit swizzle: rows spread across bank-quads (2-way = free)
__device__ __forceinline__ int frag_u(int row, int kg) {
  int bu = row >> 1;
  int inner = ((row & 1) << 2) | kg;
  return (bu << 3) | (inner ^ (bu & 7));
}

// stage 128 rows x 32 k bf16 (8KB), row stride rstride elements
__device__ __forceinline__ void stage_tile(const ushortT* __restrict__ gbase, int row0, int k0,
                                           int rstride, ushortT* lds, int w, int l) {
#pragma unroll
  for (int i = 0; i < 2; ++i) {
    int u = w * 128 + i * 64 + l;
    int bu = u >> 3;
    int inner = (u & 7) ^ (bu & 7);
    int row = bu * 2 + (inner >> 2);
    int kg = inner & 3;
    const ushortT* src = gbase + (size_t)(row0 + row) * rstride + k0 + kg * 8;
    GLOAD16(src, lds + u * 8);
  }
}

// D[r][m] = sum_k A[r][k]*Bt[m][k]; rows r = (t,c).  Writes:
//  - Dstd[r][m] (bf16, std layout) if WRITE_STD
//  - gk[b][t][m][TOFF + c]  (transposed via LDS round-trip)
template<int TOFF, bool WRITE_STD>
__global__ __launch_bounds__(256) void k_diffm(const ushortT* __restrict__ A,
                                               const ushortT* __restrict__ Bt,
                                               ushortT* __restrict__ Dstd,
                                               ushortT* __restrict__ gk) {
  __shared__ ushortT lds[16384];  // [0,8K)=A dbuf, [8K,16K)=B dbuf; reused as 128x128 TLDS
  const int tid = threadIdx.x, l = tid & 63, w = tid >> 6;
  const int wr = w >> 1, wc = w & 1;
  const int m0 = blockIdx.x * 128, r0 = blockIdx.y * 128;
  const int b = blockIdx.z;
  const ushortT* __restrict__ Ab = A + (size_t)b * R_ * NP_;
  const ushortT* __restrict__ Bb = Bt + (size_t)b * NP_ * NP_;

  f32x4 acc[4][4];
#pragma unroll
  for (int i = 0; i < 4; ++i)
#pragma unroll
    for (int j = 0; j < 4; ++j) acc[i][j] = f32x4{0.f, 0.f, 0.f, 0.f};

  stage_tile(Ab, r0, 0, NP_, lds, w, l);
  stage_tile(Bb, m0, 0, NP_, lds + 8192, w, l);
  asm volatile("s_waitcnt vmcnt(0)" ::: "memory");
  __syncthreads();

  const int kg = l >> 4, rl = l & 15;
  for (int kt = 0; kt < 28; ++kt) {
    const int pb = kt & 1;
    if (kt < 27) {
      stage_tile(Ab, r0, (kt + 1) * 32, NP_, lds + (pb ^ 1) * 4096, w, l);
      stage_tile(Bb, m0, (kt + 1) * 32, NP_, lds + 8192 + (pb ^ 1) * 4096, w, l);
    }
    bf16x8 af[4], bfr[4];
#pragma unroll
    for (int fi = 0; fi < 4; ++fi)
      af[fi] = *(const bf16x8*)&lds[pb * 4096 + frag_u(wr * 64 + fi * 16 + rl, kg) * 8];
#pragma unroll
    for (int fj = 0; fj < 4; ++fj)
      bfr[fj] = *(const bf16x8*)&lds[8192 + pb * 4096 + frag_u(wc * 64 + fj * 16 + rl, kg) * 8];
#pragma unroll
    for (int fi = 0; fi < 4; ++fi)
#pragma unroll
      for (int fj = 0; fj < 4; ++fj)
        acc[fi][fj] = __builtin_amdgcn_mfma_f32_16x16x32_bf16(af[fi], bfr[fj], acc[fi][fj], 0, 0, 0);
    asm volatile("s_waitcnt vmcnt(0)" ::: "memory");
    __syncthreads();
  }

  // std epilogue: C/D layout col=lane&15, row=(lane>>4)*4+reg  [m89-verified]
  if (WRITE_STD) {
#pragma unroll
    for (int fj = 0; fj < 4; ++fj) {
      int m = m0 + wc * 64 + fj * 16 + rl;
      if (m < N_) {
#pragma unroll
        for (int fi = 0; fi < 4; ++fi)
#pragma unroll
          for (int v = 0; v < 4; ++v) {
            int r = r0 + wr * 64 + fi * 16 + kg * 4 + v;
            Dstd[(size_t)r * NP_ + m] = f2bf(acc[fi][fj][v]);
          }
      }
    }
  }

  // transposed epilogue: acc -> TLDS[m_local][c_local] (XOR-swizzled) -> gk rows
  const int t = blockIdx.y;  // rows are (t,c) so r-block == t
#pragma unroll
  for (int fi = 0; fi < 4; ++fi)
#pragma unroll
    for (int fj = 0; fj < 4; ++fj) {
      int cb = wr * 64 + fi * 16 + kg * 4;   // c_local (= r_local), 4 consecutive via v
      int mm = wc * 64 + fj * 16 + rl;       // m_local
      ushort4 pk;
      pk.x = f2bf(acc[fi][fj][0]); pk.y = f2bf(acc[fi][fj][1]);
      pk.z = f2bf(acc[fi][fj][2]); pk.w = f2bf(acc[fi][fj][3]);
      *(ushort4*)((char*)lds + mm * 256 + ((cb * 2) ^ ((mm & 7) << 4))) = pk;
    }
  __syncthreads();
  ushortT* __restrict__ gkb = gk + (((size_t)b * T_ + t) * NP_ + m0) * KI_ + TOFF;
#pragma unroll
  for (int i = 0; i < 8; ++i) {
    int slot = i * 256 + tid;
    int mm = slot >> 4, u = slot & 15;
    uint4 vv = *(const uint4*)((const char*)lds + mm * 256 + ((u ^ (mm & 7)) << 4));
    *(uint4*)(gkb + (size_t)mm * KI_ + u * 8) = vv;  // 16 lanes -> 256B contiguous
  }
}

// ---------------- out = (gcn_w.[g1;g2] + gcn_b)*emb + x via MFMA ----------------
// per (b,t): D[o][n] = sum_i Wb[o][i] * gk[b][t][n][i]
__global__ __launch_bounds__(256) void k_outm(const ushortT* __restrict__ Wb,
                                              const ushortT* __restrict__ gk,
                                              const float* __restrict__ gcn_b,
                                              const float* __restrict__ emb,
                                              const float* __restrict__ x,
                                              float* __restrict__ out) {
  __shared__ ushortT lds[16384];
  const int tid = threadIdx.x, l = tid & 63, w = tid >> 6;
  const int wr = w >> 1, wc = w & 1;
  const int bx = blockIdx.x;
  const int t = bx % T_, ntile = bx / T_;   // t fastest: 12 t-siblings merge lines in L2
  const int n0 = ntile * 128;
  const int b = blockIdx.y;
  const ushortT* __restrict__ Bb = gk + (((size_t)b * T_ + t) * NP_ + n0) * KI_;

  f32x4 acc[4][4];
#pragma unroll
  for (int i = 0; i < 4; ++i)
#pragma unroll
    for (int j = 0; j < 4; ++j) acc[i][j] = f32x4{0.f, 0.f, 0.f, 0.f};

  stage_tile(Wb, 0, 0, KI_, lds, w, l);
  stage_tile(Bb, 0, 0, KI_, lds + 8192, w, l);
  asm volatile("s_waitcnt vmcnt(0)" ::: "memory");
  __syncthreads();

  const int kg = l >> 4, rl = l & 15;
  for (int kt = 0; kt < 8; ++kt) {
    const int pb = kt & 1;
    if (kt < 7) {
      stage_tile(Wb, 0, (kt + 1) * 32, KI_, lds + (pb ^ 1) * 4096, w, l);
      stage_tile(Bb, 0, (kt + 1) * 32, KI_, lds + 8192 + (pb ^ 1) * 4096, w, l);
    }
    bf16x8 af[4], bfr[4];
#pragma unroll
    for (int fi = 0; fi < 4; ++fi)
      af[fi] = *(const bf16x8*)&lds[pb * 4096 + frag_u(wr * 64 + fi * 16 + rl, kg) * 8];
#pragma unroll
    for (int fj = 0; fj < 4; ++fj)
      bfr[fj] = *(const bf16x8*)&lds[8192 + pb * 4096 + frag_u(wc * 64 + fj * 16 + rl, kg) * 8];
#pragma unroll
    for (int fi = 0; fi < 4; ++fi)
#pragma unroll
      for (int fj = 0; fj < 4; ++fj)
        acc[fi][fj] = __builtin_amdgcn_mfma_f32_16x16x32_bf16(af[fi], bfr[fj], acc[fi][fj], 0, 0, 0);
    asm volatile("s_waitcnt vmcnt(0)" ::: "memory");
    __syncthreads();
  }

  // epilogue: out[b][o][node][t] = (acc + gcn_b[o])*emb[o] + x[...]
#pragma unroll
  for (int fj = 0; fj < 4; ++fj) {
    int node = n0 + wc * 64 + fj * 16 + rl;
    if (node < N_) {
#pragma unroll
      for (int fi = 0; fi < 4; ++fi) {
#pragma unroll
        for (int v = 0; v < 4; ++v) {
          int o = wr * 64 + fi * 16 + kg * 4 + v;
          size_t off = (((size_t)b * C_ + o) * N_ + node) * T_ + t;
          out[off] = (acc[fi][fj][v] + gcn_b[o]) * emb[o] + x[off];
        }
      }
    }
  }
}

extern "C" void kernel_launch(void* const* d_in, const int* in_sizes, int n_in,
                              void* d_out, int out_size, void* d_ws, size_t ws_size,
                              hipStream_t stream) {
  const float* x      = (const float*)d_in[0];
  const float* conv_w = (const float*)d_in[1];
  const float* conv_b = (const float*)d_in[2];
  const float* memory = (const float*)d_in[3];
  const float* fc_w   = (const float*)d_in[4];
  const float* fc_b   = (const float*)d_in[5];
  const float* gcn_w  = (const float*)d_in[6];
  const float* gcn_b  = (const float*)d_in[7];
  const float* emb    = (const float*)d_in[8];
  float* out = (float*)d_out;

  // workspace layout. gk (176.2MB) reuses h+xs (188.1MB, dead after k_hb/k_scores);
  // g1std (88.1MB) reuses S1b+S2b (99.8MB, dead after k_adj). Peak = 427.6 MB.
  char* p = (char*)d_ws;
  float*   h      = (float*)p;    p += (size_t)B_ * C_ * N_ * T_ * 4;   // 173.6 MB
  float*   xs     = (float*)p;    p += (size_t)B_ * C_ * N_ * 4;        //  14.5 MB
  ushortT* S1b    = (ushortT*)p;  p += (size_t)B_ * N_ * N_ * 2;        //  49.9 MB
  ushortT* S2b    = (ushortT*)p;  p += (size_t)B_ * N_ * N_ * 2;        //  49.9 MB
  ushortT* adjT   = (ushortT*)p;  p += (size_t)B_ * NP_ * NP_ * 2;      //  51.4 MB
  ushortT* hb     = (ushortT*)p;  p += (size_t)B_ * R_ * NP_ * 2;       //  88.1 MB
  float*   wT     = (float*)p;    p += C_ * C_ * 4;
  ushortT* gcn_wb = (ushortT*)p;  p += C_ * KI_ * 2;
  ushortT* gk     = (ushortT*)h;    // B*T*NP*KI*2 = 176.2 MB
  ushortT* g1std  = (ushortT*)S1b;  // B*R*NP*2    =  88.1 MB

  k_transpose<<<dim3(128), dim3(256), 0, stream>>>(conv_w, gcn_w, wT, gcn_wb);
  k_conv<<<dim3(N_, B_), dim3(128), 0, stream>>>(x, wT, conv_b, h);
  k_xs<<<dim3((B_ * C_ * N_ + 255) / 256), dim3(256), 0, stream>>>(h, xs);
  k_hb<<<dim3(C_, B_), dim3(256), 0, stream>>>(h, hb);
  k_scores<<<dim3(4, 56, B_), dim3(256), 0, stream>>>(xs, memory, S1b, S2b);
  k_adj<<<dim3(N_, B_), dim3(256), 0, stream>>>(S1b, S2b, fc_w, fc_b, adjT);
  hipMemsetAsync(g1std, 0, (size_t)B_ * R_ * NP_ * 2, stream);  // zero K-pad for GEMM2
  k_diffm<0, true><<<dim3(7, 12, B_), dim3(256), 0, stream>>>(hb, adjT, g1std, gk);
  k_diffm<128, false><<<dim3(7, 12, B_), dim3(256), 0, stream>>>(g1std, adjT, nullptr, gk);
  k_outm<<<dim3(84, B_), dim3(256), 0, stream>>>(gcn_wb, gk, gcn_b, emb, x, out);
}

// Round 5
// 1861.547 us; speedup vs baseline: 4.0728x; 1.2613x over previous
//
#include <hip/hip_runtime.h>
#include <hip/hip_bf16.h>
#include <float.h>

#define B_ 32
#define C_ 128
#define N_ 883
#define T_ 12
#define K_ 706        // int(883*0.8)
#define NP_ 896       // N padded to multiple of 32
#define R_ 1536       // C_*T_
#define KI_ 256       // k_out contraction size (2*C_)
#define NT_ 10596     // N_*T_
#define SCALE_ 0.08838834764831845f  // 1/sqrt(128)

typedef unsigned short ushortT;
typedef float f32x4 __attribute__((ext_vector_type(4)));
typedef __bf16 bf16x8 __attribute__((ext_vector_type(8)));

__device__ __forceinline__ ushortT f2bf(float f) {
  union { __hip_bfloat16 h; ushortT u; } cv; cv.h = __float2bfloat16(f); return cv.u;
}
__device__ __forceinline__ float bf2f(ushortT u) {
  union { __hip_bfloat16 h; ushortT u; } cv; cv.u = u; return __bfloat162float(cv.h);
}

// 12-wide FMA into acc[] from three float4 loads
#define FMA12(a, h0, h1, h2) \
  acc[0] += (a)*(h0).x; acc[1] += (a)*(h0).y; acc[2] += (a)*(h0).z; acc[3] += (a)*(h0).w; \
  acc[4] += (a)*(h1).x; acc[5] += (a)*(h1).y; acc[6] += (a)*(h1).z; acc[7] += (a)*(h1).w; \
  acc[8] += (a)*(h2).x; acc[9] += (a)*(h2).y; acc[10] += (a)*(h2).z; acc[11] += (a)*(h2).w;

// ---------------- block reduction helpers (256 threads = 4 waves) ----------------
__device__ __forceinline__ float blockMaxF(float v, volatile float* sh, int lane, int wid) {
#pragma unroll
  for (int o = 32; o; o >>= 1) v = fmaxf(v, __shfl_xor(v, o));
  if (lane == 0) sh[wid] = v;
  __syncthreads();
  v = fmaxf(fmaxf(sh[0], sh[1]), fmaxf(sh[2], sh[3]));
  __syncthreads();
  return v;
}
__device__ __forceinline__ float blockSumF(float v, volatile float* sh, int lane, int wid) {
#pragma unroll
  for (int o = 32; o; o >>= 1) v += __shfl_xor(v, o);
  if (lane == 0) sh[wid] = v;
  __syncthreads();
  v = sh[0] + sh[1] + sh[2] + sh[3];
  __syncthreads();
  return v;
}
__device__ __forceinline__ int blockSumI(int v, volatile int* sh, int lane, int wid) {
#pragma unroll
  for (int o = 32; o; o >>= 1) v += __shfl_xor(v, o);
  if (lane == 0) sh[wid] = v;
  __syncthreads();
  v = sh[0] + sh[1] + sh[2] + sh[3];
  __syncthreads();
  return v;
}

// -------- weight prep: wT (fp32 transpose), gcn_wb (bf16), memT (bf16 transpose) --------
__global__ void k_transpose(const float* __restrict__ conv_w, const float* __restrict__ gcn_w,
                            const float* __restrict__ mem,
                            float* __restrict__ wT, ushortT* __restrict__ gcn_wb,
                            ushortT* __restrict__ memT) {
  int idx = blockIdx.x * 256 + threadIdx.x;
  if (idx < C_ * C_) {           // wT[c][o] = conv_w[o][c]
    int o = idx / C_, c = idx % C_;
    wT[c * C_ + o] = conv_w[idx];
  }
  if (idx < C_ * KI_) {          // gcn_wb[o][i] = bf16(gcn_w[o][i])
    gcn_wb[idx] = f2bf(gcn_w[idx]);
  }
  if (idx < C_ * N_) {           // memT[m][c] = bf16(mem[c][m])
    int c = idx / N_, m = idx % N_;
    memT[m * C_ + c] = f2bf(mem[idx]);
  }
}

// ---------------- h = conv_w . x + conv_b   (lane = output channel o) ----------------
__global__ __launch_bounds__(128) void k_conv(const float* __restrict__ x,
                                              const float* __restrict__ wT,
                                              const float* __restrict__ conv_b,
                                              float* __restrict__ h) {
  const int n = blockIdx.x, b = blockIdx.y, o = threadIdx.x;
  const float* __restrict__ xb = x + (size_t)b * C_ * N_ * T_ + (size_t)n * T_;
  float acc[T_];
#pragma unroll
  for (int t = 0; t < T_; ++t) acc[t] = 0.f;
#pragma unroll 4
  for (int c = 0; c < C_; ++c) {
    float w = wT[c * C_ + o];                                     // coalesced
    const float4* xp = (const float4*)(xb + (size_t)c * N_ * T_); // wave-uniform
    float4 h0 = xp[0], h1 = xp[1], h2 = xp[2];
    FMA12(w, h0, h1, h2);
  }
  float cb = conv_b[o];
  float* __restrict__ hp = h + (((size_t)b * C_ + o) * N_ + n) * T_;
  ((float4*)hp)[0] = make_float4(acc[0] + cb, acc[1] + cb, acc[2] + cb, acc[3] + cb);
  ((float4*)hp)[1] = make_float4(acc[4] + cb, acc[5] + cb, acc[6] + cb, acc[7] + cb);
  ((float4*)hp)[2] = make_float4(acc[8] + cb, acc[9] + cb, acc[10] + cb, acc[11] + cb);
}

// ---------------- xs[b][c][n] = sum_t h[b][c][n][t] ----------------
__global__ void k_xs(const float* __restrict__ h, float* __restrict__ xs) {
  int idx = blockIdx.x * 256 + threadIdx.x;
  if (idx >= B_ * C_ * N_) return;
  const float4* p = (const float4*)(h + (size_t)idx * T_);
  float4 a = p[0], b = p[1], c = p[2];
  xs[idx] = (a.x + a.y + a.z + a.w) + (b.x + b.y + b.z + b.w) + (c.x + c.y + c.z + c.w);
}

// ---------------- xsT[b][n][c] = bf16(xs[b][c][n])  (32x32 LDS transpose) ----------------
__global__ __launch_bounds__(256) void k_xsT(const float* __restrict__ xs,
                                             ushortT* __restrict__ xsT) {
  __shared__ float lt[32][33];
  const int tx = threadIdx.x & 31, ty = threadIdx.x >> 5;   // ty in [0,8)
  const int n0 = blockIdx.x * 32, c0 = blockIdx.y * 32, b = blockIdx.z;
  const float* __restrict__ xsb = xs + (size_t)b * C_ * N_;
#pragma unroll
  for (int i = 0; i < 4; ++i) {
    int c = c0 + ty + i * 8, n = n0 + tx;
    lt[ty + i * 8][tx] = (n < N_) ? xsb[(size_t)c * N_ + n] : 0.f;
  }
  __syncthreads();
  ushortT* __restrict__ ob = xsT + (size_t)b * NP_ * C_;
#pragma unroll
  for (int i = 0; i < 4; ++i) {
    int n = n0 + ty + i * 8, c = c0 + tx;
    ob[(size_t)n * C_ + c] = f2bf(lt[tx][ty + i * 8]);
  }
}

// ---------------- shared MFMA GEMM machinery ----------------
#define GLOAD16(gp, lp) __builtin_amdgcn_global_load_lds( \
    (const __attribute__((address_space(1))) unsigned int*)(gp), \
    (__attribute__((address_space(3))) unsigned int*)(lp), 16, 0, 0)

// bijective 16B-unit swizzle: rows spread across bank-quads (2-way = free)
__device__ __forceinline__ int frag_u(int row, int kg) {
  int bu = row >> 1;
  int inner = ((row & 1) << 2) | kg;
  return (bu << 3) | (inner ^ (bu & 7));
}

// stage 128 rows x 32 k bf16 (8KB), row stride rstride elements
__device__ __forceinline__ void stage_tile(const ushortT* __restrict__ gbase, int row0, int k0,
                                           int rstride, ushortT* lds, int w, int l) {
#pragma unroll
  for (int i = 0; i < 2; ++i) {
    int u = w * 128 + i * 64 + l;
    int bu = u >> 3;
    int inner = (u & 7) ^ (bu & 7);
    int row = bu * 2 + (inner >> 2);
    int kg = inner & 3;
    const ushortT* src = gbase + (size_t)(row0 + row) * rstride + k0 + kg * 8;
    GLOAD16(src, lds + u * 8);
  }
}

// ---- S1 = relu(scale * xsT . memT^T), S2 = relu(scale * xsT . xsT^T), [n][m] stride NP ----
__global__ __launch_bounds__(256) void k_scoresm(const ushortT* __restrict__ xsT,
                                                 const ushortT* __restrict__ memT,
                                                 ushortT* __restrict__ S1,
                                                 ushortT* __restrict__ S2) {
  __shared__ ushortT lds[24576];  // A dbuf [0,8K), B1 dbuf [8K,16K), B2 dbuf [16K,24K) (ushorts)
  const int tid = threadIdx.x, l = tid & 63, w = tid >> 6;
  const int wr = w >> 1, wc = w & 1;
  const int m0 = blockIdx.x * 128, n0 = blockIdx.y * 128;
  const int b = blockIdx.z;
  const ushortT* __restrict__ Ab = xsT + (size_t)b * NP_ * C_;

  f32x4 acc1[4][4], acc2[4][4];
#pragma unroll
  for (int i = 0; i < 4; ++i)
#pragma unroll
    for (int j = 0; j < 4; ++j) { acc1[i][j] = f32x4{0,0,0,0}; acc2[i][j] = f32x4{0,0,0,0}; }

  stage_tile(Ab, n0, 0, C_, lds, w, l);
  stage_tile(memT, m0, 0, C_, lds + 8192, w, l);
  stage_tile(Ab, m0, 0, C_, lds + 16384, w, l);
  asm volatile("s_waitcnt vmcnt(0)" ::: "memory");
  __syncthreads();

  const int kg = l >> 4, rl = l & 15;
  for (int kt = 0; kt < 4; ++kt) {
    const int pb = kt & 1;
    if (kt < 3) {
      stage_tile(Ab, n0, (kt + 1) * 32, C_, lds + (pb ^ 1) * 4096, w, l);
      stage_tile(memT, m0, (kt + 1) * 32, C_, lds + 8192 + (pb ^ 1) * 4096, w, l);
      stage_tile(Ab, m0, (kt + 1) * 32, C_, lds + 16384 + (pb ^ 1) * 4096, w, l);
    }
    bf16x8 af[4], b1[4], b2[4];
#pragma unroll
    for (int fi = 0; fi < 4; ++fi)
      af[fi] = *(const bf16x8*)&lds[pb * 4096 + frag_u(wr * 64 + fi * 16 + rl, kg) * 8];
#pragma unroll
    for (int fj = 0; fj < 4; ++fj) {
      b1[fj] = *(const bf16x8*)&lds[8192 + pb * 4096 + frag_u(wc * 64 + fj * 16 + rl, kg) * 8];
      b2[fj] = *(const bf16x8*)&lds[16384 + pb * 4096 + frag_u(wc * 64 + fj * 16 + rl, kg) * 8];
    }
#pragma unroll
    for (int fi = 0; fi < 4; ++fi)
#pragma unroll
      for (int fj = 0; fj < 4; ++fj) {
        acc1[fi][fj] = __builtin_amdgcn_mfma_f32_16x16x32_bf16(af[fi], b1[fj], acc1[fi][fj], 0, 0, 0);
        acc2[fi][fj] = __builtin_amdgcn_mfma_f32_16x16x32_bf16(af[fi], b2[fj], acc2[fi][fj], 0, 0, 0);
      }
    asm volatile("s_waitcnt vmcnt(0)" ::: "memory");
    __syncthreads();
  }

#pragma unroll
  for (int fj = 0; fj < 4; ++fj) {
    int m = m0 + wc * 64 + fj * 16 + rl;
#pragma unroll
    for (int fi = 0; fi < 4; ++fi)
#pragma unroll
      for (int v = 0; v < 4; ++v) {
        int n = n0 + wr * 64 + fi * 16 + kg * 4 + v;
        size_t off = ((size_t)b * NP_ + n) * NP_ + m;
        S1[off] = f2bf(fmaxf(acc1[fi][fj][v] * SCALE_, 0.f));
        S2[off] = f2bf(fmaxf(acc2[fi][fj][v] * SCALE_, 0.f));
      }
  }
}

// ------- hb[b][t*128+c][n] = bf16(h[b][c][n][t]), rows (t,c), n padded w/ zeros -------
__global__ __launch_bounds__(256) void k_hb(const float* __restrict__ h,
                                            ushortT* __restrict__ hb) {
  const int c = blockIdx.x, b = blockIdx.y, tid = threadIdx.x;
  __shared__ ushortT lt[T_ * NP_];  // 21 KB
  const float* __restrict__ hp = h + ((size_t)(b * C_ + c)) * (N_ * T_);
  for (int j = tid; j < N_ * T_; j += 256) {
    int n = j / T_, t = j - n * T_;              // coalesced read of h
    lt[t * NP_ + n] = f2bf(hp[j]);
  }
  __syncthreads();
  ushortT* __restrict__ ob = hb + (size_t)b * R_ * NP_;
  for (int j = tid; j < T_ * NP_; j += 256) {
    int t = j / NP_, n = j - t * NP_;
    ob[(size_t)(t * C_ + c) * NP_ + n] = (n < N_) ? lt[j] : (ushortT)0;  // zero K-pad
  }
}

// ---------------- per-(b,n) row: softmaxes, fc, softmax, topk -> adjT bf16 ----------------
__global__ __launch_bounds__(256) void k_adj(const ushortT* __restrict__ S1,
                                             const ushortT* __restrict__ S2,
                                             const float* __restrict__ fc_w,
                                             const float* __restrict__ fc_b,
                                             ushortT* __restrict__ adjT) {
  const int n = blockIdx.x, b = blockIdx.y;
  const int tid = threadIdx.x, lane = tid & 63, wid = tid >> 6;
  __shared__ float shf[4];
  __shared__ int shi[4];
  const size_t roff = ((size_t)b * NP_ + n) * NP_;

  float v1[4], v2[4];
  bool val[4];
#pragma unroll
  for (int j = 0; j < 4; ++j) {
    int m = j * 256 + tid;
    val[j] = (m < N_);
    int mc = val[j] ? m : 0;
    v1[j] = bf2f(S1[roff + mc]);
    v2[j] = bf2f(S2[roff + mc]);
  }
  float mx = -FLT_MAX;
#pragma unroll
  for (int j = 0; j < 4; ++j) if (val[j]) mx = fmaxf(mx, v1[j]);
  mx = blockMaxF(mx, shf, lane, wid);
  float sm = 0.f;
#pragma unroll
  for (int j = 0; j < 4; ++j) { float e = val[j] ? __expf(v1[j] - mx) : 0.f; v1[j] = e; sm += e; }
  sm = blockSumF(sm, shf, lane, wid);
  const float inv1 = 1.f / sm;
  mx = -FLT_MAX;
#pragma unroll
  for (int j = 0; j < 4; ++j) if (val[j]) mx = fmaxf(mx, v2[j]);
  mx = blockMaxF(mx, shf, lane, wid);
  sm = 0.f;
#pragma unroll
  for (int j = 0; j < 4; ++j) { float e = val[j] ? __expf(v2[j] - mx) : 0.f; v2[j] = e; sm += e; }
  sm = blockSumF(sm, shf, lane, wid);
  const float inv2 = 1.f / sm;
  const float w0 = fc_w[0], w1 = fc_w[1], fb = fc_b[0];
#pragma unroll
  for (int j = 0; j < 4; ++j) v1[j] = w0 * (v1[j] * inv1) + w1 * (v2[j] * inv2) + fb;
  mx = -FLT_MAX;
#pragma unroll
  for (int j = 0; j < 4; ++j) if (val[j]) mx = fmaxf(mx, v1[j]);
  mx = blockMaxF(mx, shf, lane, wid);
  sm = 0.f;
#pragma unroll
  for (int j = 0; j < 4; ++j) { float e = val[j] ? __expf(v1[j] - mx) : 0.f; v1[j] = e; sm += e; }
  sm = blockSumF(sm, shf, lane, wid);
  const float inv3 = 1.f / sm;

  unsigned ui[4];
#pragma unroll
  for (int j = 0; j < 4; ++j) ui[j] = val[j] ? __float_as_uint(v1[j]) : 0u;
  unsigned lo = 0u;
  for (int bit = 30; bit >= 0; --bit) {
    unsigned cand = lo | (1u << bit);
    int lc = 0;
#pragma unroll
    for (int j = 0; j < 4; ++j) lc += (ui[j] >= cand) ? 1 : 0;
    int cnt = blockSumI(lc, shi, lane, wid);
    if (cnt >= K_) lo = cand;
  }
  int gl = 0;
#pragma unroll
  for (int j = 0; j < 4; ++j) gl += (ui[j] > lo) ? 1 : 0;
  const int G = blockSumI(gl, shi, lane, wid);
  const int take = K_ - G;  // ties kept by smallest index (lax.top_k stability)

  ushortT* __restrict__ aT = adjT + (size_t)b * NP_ * NP_;
  int base = 0;
  for (int j = 0; j < 4; ++j) {
    bool eq = val[j] && (ui[j] == lo);
    unsigned long long ball = __ballot(eq ? 1 : 0);
    if (lane == 0) shi[wid] = __popcll(ball);
    __syncthreads();
    int wpre = 0, tot = 0;
#pragma unroll
    for (int w = 0; w < 4; ++w) { int cw = shi[w]; if (w < wid) wpre += cw; tot += cw; }
    __syncthreads();
    int lpre = __builtin_amdgcn_mbcnt_hi((unsigned)(ball >> 32),
                                         __builtin_amdgcn_mbcnt_lo((unsigned)ball, 0u));
    int rank = base + wpre + lpre;
    bool keep = val[j] && ((ui[j] > lo) || (eq && rank < take));
    int m = j * 256 + tid;
    if (val[j]) aT[(size_t)m * NP_ + n] = keep ? f2bf(v1[j] * inv3) : (ushortT)0;
    base += tot;
  }
}

// D[r][m] = sum_k A[r][k]*Bt[m][k]; rows r = (t,c).  Writes:
//  - Dstd[r][m] (bf16, std layout) if WRITE_STD
//  - gk[b][node][t][TOFF + c]  (node-major: flat col of final GEMM = node*T+t)
template<int TOFF, bool WRITE_STD>
__global__ __launch_bounds__(256) void k_diffm(const ushortT* __restrict__ A,
                                               const ushortT* __restrict__ Bt,
                                               ushortT* __restrict__ Dstd,
                                               ushortT* __restrict__ gk) {
  __shared__ ushortT lds[16384];  // [0,8K)=A dbuf, [8K,16K)=B dbuf; reused as 128x128 TLDS
  const int tid = threadIdx.x, l = tid & 63, w = tid >> 6;
  const int wr = w >> 1, wc = w & 1;
  const int m0 = blockIdx.x * 128, r0 = blockIdx.y * 128;
  const int b = blockIdx.z;
  const ushortT* __restrict__ Ab = A + (size_t)b * R_ * NP_;
  const ushortT* __restrict__ Bb = Bt + (size_t)b * NP_ * NP_;

  f32x4 acc[4][4];
#pragma unroll
  for (int i = 0; i < 4; ++i)
#pragma unroll
    for (int j = 0; j < 4; ++j) acc[i][j] = f32x4{0.f, 0.f, 0.f, 0.f};

  stage_tile(Ab, r0, 0, NP_, lds, w, l);
  stage_tile(Bb, m0, 0, NP_, lds + 8192, w, l);
  asm volatile("s_waitcnt vmcnt(0)" ::: "memory");
  __syncthreads();

  const int kg = l >> 4, rl = l & 15;
  for (int kt = 0; kt < 28; ++kt) {
    const int pb = kt & 1;
    if (kt < 27) {
      stage_tile(Ab, r0, (kt + 1) * 32, NP_, lds + (pb ^ 1) * 4096, w, l);
      stage_tile(Bb, m0, (kt + 1) * 32, NP_, lds + 8192 + (pb ^ 1) * 4096, w, l);
    }
    bf16x8 af[4], bfr[4];
#pragma unroll
    for (int fi = 0; fi < 4; ++fi)
      af[fi] = *(const bf16x8*)&lds[pb * 4096 + frag_u(wr * 64 + fi * 16 + rl, kg) * 8];
#pragma unroll
    for (int fj = 0; fj < 4; ++fj)
      bfr[fj] = *(const bf16x8*)&lds[8192 + pb * 4096 + frag_u(wc * 64 + fj * 16 + rl, kg) * 8];
#pragma unroll
    for (int fi = 0; fi < 4; ++fi)
#pragma unroll
      for (int fj = 0; fj < 4; ++fj)
        acc[fi][fj] = __builtin_amdgcn_mfma_f32_16x16x32_bf16(af[fi], bfr[fj], acc[fi][fj], 0, 0, 0);
    asm volatile("s_waitcnt vmcnt(0)" ::: "memory");
    __syncthreads();
  }

  // std epilogue: C/D layout col=lane&15, row=(lane>>4)*4+reg  [m89-verified]
  if (WRITE_STD) {
#pragma unroll
    for (int fj = 0; fj < 4; ++fj) {
      int m = m0 + wc * 64 + fj * 16 + rl;
      if (m < N_) {
#pragma unroll
        for (int fi = 0; fi < 4; ++fi)
#pragma unroll
          for (int v = 0; v < 4; ++v) {
            int r = r0 + wr * 64 + fi * 16 + kg * 4 + v;
            Dstd[(size_t)r * NP_ + m] = f2bf(acc[fi][fj][v]);
          }
      }
    }
  }

  // transposed epilogue: acc -> TLDS[m_local][c_local] (XOR-swizzled) -> gk node-major rows
  const int t = blockIdx.y;  // rows are (t,c) so r-block == t
#pragma unroll
  for (int fi = 0; fi < 4; ++fi)
#pragma unroll
    for (int fj = 0; fj < 4; ++fj) {
      int cb = wr * 64 + fi * 16 + kg * 4;   // c_local, 4 consecutive via v
      int mm = wc * 64 + fj * 16 + rl;       // m_local (node)
      ushort4 pk;
      pk.x = f2bf(acc[fi][fj][0]); pk.y = f2bf(acc[fi][fj][1]);
      pk.z = f2bf(acc[fi][fj][2]); pk.w = f2bf(acc[fi][fj][3]);
      *(ushort4*)((char*)lds + mm * 256 + ((cb * 2) ^ ((mm & 7) << 4))) = pk;
    }
  __syncthreads();
  ushortT* __restrict__ gkb = gk + (((size_t)b * NP_ + m0) * T_ + t) * KI_ + TOFF;
#pragma unroll
  for (int i = 0; i < 8; ++i) {
    int slot = i * 256 + tid;
    int mm = slot >> 4, u = slot & 15;
    uint4 vv = *(const uint4*)((const char*)lds + mm * 256 + ((u ^ (mm & 7)) << 4));
    *(uint4*)(gkb + (size_t)mm * (T_ * KI_) + u * 8) = vv;  // 16 lanes -> 256B contiguous
  }
}

// ------- out[b][o][m] = (sum_i W[o][i]*gk[b][m][i] + gcn_b[o])*emb[o] + x[b][o][m] -------
// m = node*T + t flat; fully coalesced stores/loads along m.
__global__ __launch_bounds__(256) void k_outm(const ushortT* __restrict__ Wb,
                                              const ushortT* __restrict__ gk,
                                              const float* __restrict__ gcn_b,
                                              const float* __restrict__ emb,
                                              const float* __restrict__ x,
                                              float* __restrict__ out) {
  __shared__ ushortT lds[16384];
  const int tid = threadIdx.x, l = tid & 63, w = tid >> 6;
  const int wr = w >> 1, wc = w & 1;
  const int m0 = blockIdx.x * 128;
  const int b = blockIdx.y;
  const ushortT* __restrict__ Bb = gk + ((size_t)b * NP_ * T_ + m0) * KI_;

  f32x4 acc[4][4];
#pragma unroll
  for (int i = 0; i < 4; ++i)
#pragma unroll
    for (int j = 0; j < 4; ++j) acc[i][j] = f32x4{0.f, 0.f, 0.f, 0.f};

  stage_tile(Wb, 0, 0, KI_, lds, w, l);
  stage_tile(Bb, 0, 0, KI_, lds + 8192, w, l);
  asm volatile("s_waitcnt vmcnt(0)" ::: "memory");
  __syncthreads();

  const int kg = l >> 4, rl = l & 15;
  for (int kt = 0; kt < 8; ++kt) {
    const int pb = kt & 1;
    if (kt < 7) {
      stage_tile(Wb, 0, (kt + 1) * 32, KI_, lds + (pb ^ 1) * 4096, w, l);
      stage_tile(Bb, 0, (kt + 1) * 32, KI_, lds + 8192 + (pb ^ 1) * 4096, w, l);
    }
    bf16x8 af[4], bfr[4];
#pragma unroll
    for (int fi = 0; fi < 4; ++fi)
      af[fi] = *(const bf16x8*)&lds[pb * 4096 + frag_u(wr * 64 + fi * 16 + rl, kg) * 8];
#pragma unroll
    for (int fj = 0; fj < 4; ++fj)
      bfr[fj] = *(const bf16x8*)&lds[8192 + pb * 4096 + frag_u(wc * 64 + fj * 16 + rl, kg) * 8];
#pragma unroll
    for (int fi = 0; fi < 4; ++fi)
#pragma unroll
      for (int fj = 0; fj < 4; ++fj)
        acc[fi][fj] = __builtin_amdgcn_mfma_f32_16x16x32_bf16(af[fi], bfr[fj], acc[fi][fj], 0, 0, 0);
    asm volatile("s_waitcnt vmcnt(0)" ::: "memory");
    __syncthreads();
  }

#pragma unroll
  for (int fj = 0; fj < 4; ++fj) {
    int m = m0 + wc * 64 + fj * 16 + rl;
    if (m < NT_) {
#pragma unroll
      for (int fi = 0; fi < 4; ++fi) {
#pragma unroll
        for (int v = 0; v < 4; ++v) {
          int o = wr * 64 + fi * 16 + kg * 4 + v;
          size_t off = ((size_t)b * C_ + o) * NT_ + m;
          out[off] = (acc[fi][fj][v] + gcn_b[o]) * emb[o] + x[off];
        }
      }
    }
  }
}

extern "C" void kernel_launch(void* const* d_in, const int* in_sizes, int n_in,
                              void* d_out, int out_size, void* d_ws, size_t ws_size,
                              hipStream_t stream) {
  const float* x      = (const float*)d_in[0];
  const float* conv_w = (const float*)d_in[1];
  const float* conv_b = (const float*)d_in[2];
  const float* memory = (const float*)d_in[3];
  const float* fc_w   = (const float*)d_in[4];
  const float* fc_b   = (const float*)d_in[5];
  const float* gcn_w  = (const float*)d_in[6];
  const float* gcn_b  = (const float*)d_in[7];
  const float* emb    = (const float*)d_in[8];
  float* out = (float*)d_out;

  // workspace layout. gk (176.2MB) reuses h+xs (188.1MB, dead after k_hb/k_xsT);
  // g1std (88.1MB) reuses S1b+S2b (102.8MB, dead after k_adj). Peak ~431 MB.
  char* p = (char*)d_ws;
  float*   h      = (float*)p;    p += (size_t)B_ * C_ * N_ * T_ * 4;   // 173.6 MB
  float*   xs     = (float*)p;    p += (size_t)B_ * C_ * N_ * 4;        //  14.5 MB
  ushortT* S1b    = (ushortT*)p;  p += (size_t)B_ * NP_ * NP_ * 2;      //  51.4 MB
  ushortT* S2b    = (ushortT*)p;  p += (size_t)B_ * NP_ * NP_ * 2;      //  51.4 MB
  ushortT* adjT   = (ushortT*)p;  p += (size_t)B_ * NP_ * NP_ * 2;      //  51.4 MB
  ushortT* hb     = (ushortT*)p;  p += (size_t)B_ * R_ * NP_ * 2;       //  88.1 MB
  float*   wT     = (float*)p;    p += C_ * C_ * 4;
  ushortT* gcn_wb = (ushortT*)p;  p += C_ * KI_ * 2;
  ushortT* memT   = (ushortT*)p;  p += (size_t)NP_ * C_ * 2;            //   0.23 MB
  ushortT* xsT    = (ushortT*)p;  p += (size_t)B_ * NP_ * C_ * 2;       //   7.3 MB
  ushortT* gk     = (ushortT*)h;    // B*NP*T*KI*2 = 176.2 MB
  ushortT* g1std  = (ushortT*)S1b;  // B*R*NP*2    =  88.1 MB

  k_transpose<<<dim3(512), dim3(256), 0, stream>>>(conv_w, gcn_w, memory, wT, gcn_wb, memT);
  k_conv<<<dim3(N_, B_), dim3(128), 0, stream>>>(x, wT, conv_b, h);
  k_xs<<<dim3((B_ * C_ * N_ + 255) / 256), dim3(256), 0, stream>>>(h, xs);
  k_hb<<<dim3(C_, B_), dim3(256), 0, stream>>>(h, hb);
  k_xsT<<<dim3(28, 4, B_), dim3(256), 0, stream>>>(xs, xsT);
  k_scoresm<<<dim3(7, 7, B_), dim3(256), 0, stream>>>(xsT, memT, S1b, S2b);
  k_adj<<<dim3(N_, B_), dim3(256), 0, stream>>>(S1b, S2b, fc_w, fc_b, adjT);
  hipMemsetAsync(g1std, 0, (size_t)B_ * R_ * NP_ * 2, stream);  // zero K-pad for GEMM2
  k_diffm<0, true><<<dim3(7, 12, B_), dim3(256), 0, stream>>>(hb, adjT, g1std, gk);
  k_diffm<128, false><<<dim3(7, 12, B_), dim3(256), 0, stream>>>(g1std, adjT, nullptr, gk);
  k_outm<<<dim3(84, B_), dim3(256), 0, stream>>>(gcn_wb, gk, gcn_b, emb, x, out);
}

// Round 6
// 1433.082 us; speedup vs baseline: 5.2904x; 1.2990x over previous
//
#include <hip/hip_runtime.h>
#include <hip/hip_bf16.h>
#include <float.h>

#define B_ 32
#define C_ 128
#define N_ 883
#define T_ 12
#define K_ 706        // int(883*0.8)
#define NP_ 896       // N padded to multiple of 32
#define R_ 1536       // C_*T_
#define KI_ 256       // k_out contraction size (2*C_)
#define NT_ 10596     // N_*T_
#define NPT_ 10752    // NP_*T_
#define SCALE_ 0.08838834764831845f  // 1/sqrt(128)

typedef unsigned short ushortT;
typedef float f32x4 __attribute__((ext_vector_type(4)));
typedef __bf16 bf16x8 __attribute__((ext_vector_type(8)));

__device__ __forceinline__ ushortT f2bf(float f) {
  union { __hip_bfloat16 h; ushortT u; } cv; cv.h = __float2bfloat16(f); return cv.u;
}
__device__ __forceinline__ float bf2f(ushortT u) {
  union { __hip_bfloat16 h; ushortT u; } cv; cv.u = u; return __bfloat162float(cv.h);
}

// ---------------- block reduction helpers (256 threads = 4 waves) ----------------
__device__ __forceinline__ float blockMaxF(float v, volatile float* sh, int lane, int wid) {
#pragma unroll
  for (int o = 32; o; o >>= 1) v = fmaxf(v, __shfl_xor(v, o));
  if (lane == 0) sh[wid] = v;
  __syncthreads();
  v = fmaxf(fmaxf(sh[0], sh[1]), fmaxf(sh[2], sh[3]));
  __syncthreads();
  return v;
}
__device__ __forceinline__ float blockSumF(float v, volatile float* sh, int lane, int wid) {
#pragma unroll
  for (int o = 32; o; o >>= 1) v += __shfl_xor(v, o);
  if (lane == 0) sh[wid] = v;
  __syncthreads();
  v = sh[0] + sh[1] + sh[2] + sh[3];
  __syncthreads();
  return v;
}
__device__ __forceinline__ int blockSumI(int v, volatile int* sh, int lane, int wid) {
#pragma unroll
  for (int o = 32; o; o >>= 1) v += __shfl_xor(v, o);
  if (lane == 0) sh[wid] = v;
  __syncthreads();
  v = sh[0] + sh[1] + sh[2] + sh[3];
  __syncthreads();
  return v;
}

// -------- weight prep: conv_wb (bf16), gcn_wb (bf16), memT (bf16 transpose) --------
__global__ void k_transpose(const float* __restrict__ conv_w, const float* __restrict__ gcn_w,
                            const float* __restrict__ mem,
                            ushortT* __restrict__ conv_wb, ushortT* __restrict__ gcn_wb,
                            ushortT* __restrict__ memT) {
  int idx = blockIdx.x * 256 + threadIdx.x;
  if (idx < C_ * C_) {           // conv_wb[o][c] = bf16(conv_w[o][c]) (k=c contiguous)
    conv_wb[idx] = f2bf(conv_w[idx]);
  }
  if (idx < C_ * KI_) {          // gcn_wb[o][i] = bf16(gcn_w[o][i])
    gcn_wb[idx] = f2bf(gcn_w[idx]);
  }
  if (idx < C_ * N_) {           // memT[m][c] = bf16(mem[c][m])
    int c = idx / N_, m = idx % N_;
    memT[m * C_ + c] = f2bf(mem[idx]);
  }
}

// ------- xTb[b][t][n][c] = bf16(x[b][c][n][t])  (LDS 32x32 transpose, both sides coalesced)
__global__ __launch_bounds__(256) void k_xT(const float* __restrict__ x,
                                            ushortT* __restrict__ xTb) {
  __shared__ float lt[32][33];
  const int tx = threadIdx.x & 31, ty = threadIdx.x >> 5;   // ty in [0,8)
  const int m0 = blockIdx.x * 32, c0 = blockIdx.y * 32, b = blockIdx.z;
  const float* __restrict__ xb = x + (size_t)b * C_ * NT_;
#pragma unroll
  for (int i = 0; i < 4; ++i) {
    int c = c0 + ty + i * 8, m = m0 + tx;
    lt[ty + i * 8][tx] = (m < NT_) ? xb[(size_t)c * NT_ + m] : 0.f;
  }
  __syncthreads();
  ushortT* __restrict__ ob = xTb + (size_t)b * T_ * NP_ * C_;
#pragma unroll
  for (int i = 0; i < 4; ++i) {
    int m = m0 + ty + i * 8;
    if (m < NT_) {
      int n = m / T_, t = m - n * T_;
      ob[((size_t)t * NP_ + n) * C_ + c0 + tx] = f2bf(lt[tx][ty + i * 8]);
    }
  }
}

// ---------------- shared MFMA GEMM machinery ----------------
#define GLOAD16(gp, lp) __builtin_amdgcn_global_load_lds( \
    (const __attribute__((address_space(1))) unsigned int*)(gp), \
    (__attribute__((address_space(3))) unsigned int*)(lp), 16, 0, 0)

// bijective 16B-unit swizzle: rows spread across bank-quads (2-way = free)
__device__ __forceinline__ int frag_u(int row, int kg) {
  int bu = row >> 1;
  int inner = ((row & 1) << 2) | kg;
  return (bu << 3) | (inner ^ (bu & 7));
}

// stage 128 rows x 32 k bf16 (8KB), row stride rstride elements
__device__ __forceinline__ void stage_tile(const ushortT* __restrict__ gbase, int row0, int k0,
                                           int rstride, ushortT* lds, int w, int l) {
#pragma unroll
  for (int i = 0; i < 2; ++i) {
    int u = w * 128 + i * 64 + l;
    int bu = u >> 3;
    int inner = (u & 7) ^ (bu & 7);
    int row = bu * 2 + (inner >> 2);
    int kg = inner & 3;
    const ushortT* src = gbase + (size_t)(row0 + row) * rstride + k0 + kg * 8;
    GLOAD16(src, lds + u * 8);
  }
}

// ------- hb[(t,o)][n] = bf16(conv_w . x + conv_b)  via MFMA, n-pad zeroed -------
// per (b, t, n-tile): A = conv_wb [o][c], B rows = xTb[b][t][n][c]
__global__ __launch_bounds__(256) void k_convm(const ushortT* __restrict__ Wb,
                                               const ushortT* __restrict__ xTb,
                                               const float* __restrict__ conv_b,
                                               ushortT* __restrict__ hb) {
  __shared__ ushortT lds[16384];
  const int tid = threadIdx.x, l = tid & 63, w = tid >> 6;
  const int wr = w >> 1, wc = w & 1;
  const int n0 = blockIdx.x * 128, t = blockIdx.y, b = blockIdx.z;
  const ushortT* __restrict__ Bb = xTb + ((size_t)b * T_ + t) * NP_ * C_;

  f32x4 acc[4][4];
#pragma unroll
  for (int i = 0; i < 4; ++i)
#pragma unroll
    for (int j = 0; j < 4; ++j) acc[i][j] = f32x4{0.f, 0.f, 0.f, 0.f};

  stage_tile(Wb, 0, 0, C_, lds, w, l);
  stage_tile(Bb, n0, 0, C_, lds + 8192, w, l);
  asm volatile("s_waitcnt vmcnt(0)" ::: "memory");
  __syncthreads();

  const int kg = l >> 4, rl = l & 15;
  for (int kt = 0; kt < 4; ++kt) {
    const int pb = kt & 1;
    if (kt < 3) {
      stage_tile(Wb, 0, (kt + 1) * 32, C_, lds + (pb ^ 1) * 4096, w, l);
      stage_tile(Bb, n0, (kt + 1) * 32, C_, lds + 8192 + (pb ^ 1) * 4096, w, l);
    }
    bf16x8 af[4], bfr[4];
#pragma unroll
    for (int fi = 0; fi < 4; ++fi)
      af[fi] = *(const bf16x8*)&lds[pb * 4096 + frag_u(wr * 64 + fi * 16 + rl, kg) * 8];
#pragma unroll
    for (int fj = 0; fj < 4; ++fj)
      bfr[fj] = *(const bf16x8*)&lds[8192 + pb * 4096 + frag_u(wc * 64 + fj * 16 + rl, kg) * 8];
#pragma unroll
    for (int fi = 0; fi < 4; ++fi)
#pragma unroll
      for (int fj = 0; fj < 4; ++fj)
        acc[fi][fj] = __builtin_amdgcn_mfma_f32_16x16x32_bf16(af[fi], bfr[fj], acc[fi][fj], 0, 0, 0);
    asm volatile("s_waitcnt vmcnt(0)" ::: "memory");
    __syncthreads();
  }

  // epilogue: rows o, cols n -> hb[(t*C+o)][n]; zero the n-pad (GEMM1 contracts over n)
  ushortT* __restrict__ hbb = hb + (size_t)b * R_ * NP_ + (size_t)t * C_ * NP_;
#pragma unroll
  for (int fj = 0; fj < 4; ++fj) {
    int n = n0 + wc * 64 + fj * 16 + rl;
    bool vn = (n < N_);
#pragma unroll
    for (int fi = 0; fi < 4; ++fi) {
      int ob = wr * 64 + fi * 16 + kg * 4;
#pragma unroll
      for (int v = 0; v < 4; ++v) {
        float cb = conv_b[ob + v];
        hbb[(size_t)(ob + v) * NP_ + n] = vn ? f2bf(acc[fi][fj][v] + cb) : (ushortT)0;
      }
    }
  }
}

// ---- xsT[b][n][c] = bf16(sum_t hb[(t,c)][n])  (LDS 32x32 transpose; pad rows -> 0) ----
__global__ __launch_bounds__(256) void k_xsT2(const ushortT* __restrict__ hb,
                                              ushortT* __restrict__ xsT) {
  __shared__ float lt[32][33];
  const int tx = threadIdx.x & 31, ty = threadIdx.x >> 5;
  const int n0 = blockIdx.x * 32, c0 = blockIdx.y * 32, b = blockIdx.z;
  const ushortT* __restrict__ hbb = hb + (size_t)b * R_ * NP_;
#pragma unroll
  for (int i = 0; i < 4; ++i) {
    int c = c0 + ty + i * 8, n = n0 + tx;
    float s = 0.f;
#pragma unroll
    for (int t = 0; t < T_; ++t)
      s += bf2f(hbb[((size_t)t * C_ + c) * NP_ + n]);
    lt[ty + i * 8][tx] = s;   // hb n-pad is zero -> pad sums are 0
  }
  __syncthreads();
  ushortT* __restrict__ ob = xsT + (size_t)b * NP_ * C_;
#pragma unroll
  for (int i = 0; i < 4; ++i) {
    int n = n0 + ty + i * 8;
    ob[(size_t)n * C_ + c0 + tx] = f2bf(lt[tx][ty + i * 8]);
  }
}

// ---- S1 = relu(scale * xsT . memT^T), S2 = relu(scale * xsT . xsT^T), [n][m] stride NP ----
__global__ __launch_bounds__(256) void k_scoresm(const ushortT* __restrict__ xsT,
                                                 const ushortT* __restrict__ memT,
                                                 ushortT* __restrict__ S1,
                                                 ushortT* __restrict__ S2) {
  __shared__ ushortT lds[24576];
  const int tid = threadIdx.x, l = tid & 63, w = tid >> 6;
  const int wr = w >> 1, wc = w & 1;
  const int m0 = blockIdx.x * 128, n0 = blockIdx.y * 128;
  const int b = blockIdx.z;
  const ushortT* __restrict__ Ab = xsT + (size_t)b * NP_ * C_;

  f32x4 acc1[4][4], acc2[4][4];
#pragma unroll
  for (int i = 0; i < 4; ++i)
#pragma unroll
    for (int j = 0; j < 4; ++j) { acc1[i][j] = f32x4{0,0,0,0}; acc2[i][j] = f32x4{0,0,0,0}; }

  stage_tile(Ab, n0, 0, C_, lds, w, l);
  stage_tile(memT, m0, 0, C_, lds + 8192, w, l);
  stage_tile(Ab, m0, 0, C_, lds + 16384, w, l);
  asm volatile("s_waitcnt vmcnt(0)" ::: "memory");
  __syncthreads();

  const int kg = l >> 4, rl = l & 15;
  for (int kt = 0; kt < 4; ++kt) {
    const int pb = kt & 1;
    if (kt < 3) {
      stage_tile(Ab, n0, (kt + 1) * 32, C_, lds + (pb ^ 1) * 4096, w, l);
      stage_tile(memT, m0, (kt + 1) * 32, C_, lds + 8192 + (pb ^ 1) * 4096, w, l);
      stage_tile(Ab, m0, (kt + 1) * 32, C_, lds + 16384 + (pb ^ 1) * 4096, w, l);
    }
    bf16x8 af[4], b1[4], b2[4];
#pragma unroll
    for (int fi = 0; fi < 4; ++fi)
      af[fi] = *(const bf16x8*)&lds[pb * 4096 + frag_u(wr * 64 + fi * 16 + rl, kg) * 8];
#pragma unroll
    for (int fj = 0; fj < 4; ++fj) {
      b1[fj] = *(const bf16x8*)&lds[8192 + pb * 4096 + frag_u(wc * 64 + fj * 16 + rl, kg) * 8];
      b2[fj] = *(const bf16x8*)&lds[16384 + pb * 4096 + frag_u(wc * 64 + fj * 16 + rl, kg) * 8];
    }
#pragma unroll
    for (int fi = 0; fi < 4; ++fi)
#pragma unroll
      for (int fj = 0; fj < 4; ++fj) {
        acc1[fi][fj] = __builtin_amdgcn_mfma_f32_16x16x32_bf16(af[fi], b1[fj], acc1[fi][fj], 0, 0, 0);
        acc2[fi][fj] = __builtin_amdgcn_mfma_f32_16x16x32_bf16(af[fi], b2[fj], acc2[fi][fj], 0, 0, 0);
      }
    asm volatile("s_waitcnt vmcnt(0)" ::: "memory");
    __syncthreads();
  }

#pragma unroll
  for (int fj = 0; fj < 4; ++fj) {
    int m = m0 + wc * 64 + fj * 16 + rl;
#pragma unroll
    for (int fi = 0; fi < 4; ++fi)
#pragma unroll
      for (int v = 0; v < 4; ++v) {
        int n = n0 + wr * 64 + fi * 16 + kg * 4 + v;
        size_t off = ((size_t)b * NP_ + n) * NP_ + m;
        S1[off] = f2bf(fmaxf(acc1[fi][fj][v] * SCALE_, 0.f));
        S2[off] = f2bf(fmaxf(acc2[fi][fj][v] * SCALE_, 0.f));
      }
  }
}

// ---------------- per-(b,n) row: softmaxes, fc, softmax, topk -> adjT bf16 ----------------
__global__ __launch_bounds__(256) void k_adj(const ushortT* __restrict__ S1,
                                             const ushortT* __restrict__ S2,
                                             const float* __restrict__ fc_w,
                                             const float* __restrict__ fc_b,
                                             ushortT* __restrict__ adjT) {
  const int n = blockIdx.x, b = blockIdx.y;
  const int tid = threadIdx.x, lane = tid & 63, wid = tid >> 6;
  __shared__ float shf[4];
  __shared__ int shi[4];
  const size_t roff = ((size_t)b * NP_ + n) * NP_;

  float v1[4], v2[4];
  bool val[4];
#pragma unroll
  for (int j = 0; j < 4; ++j) {
    int m = j * 256 + tid;
    val[j] = (m < N_);
    int mc = val[j] ? m : 0;
    v1[j] = bf2f(S1[roff + mc]);
    v2[j] = bf2f(S2[roff + mc]);
  }
  float mx = -FLT_MAX;
#pragma unroll
  for (int j = 0; j < 4; ++j) if (val[j]) mx = fmaxf(mx, v1[j]);
  mx = blockMaxF(mx, shf, lane, wid);
  float sm = 0.f;
#pragma unroll
  for (int j = 0; j < 4; ++j) { float e = val[j] ? __expf(v1[j] - mx) : 0.f; v1[j] = e; sm += e; }
  sm = blockSumF(sm, shf, lane, wid);
  const float inv1 = 1.f / sm;
  mx = -FLT_MAX;
#pragma unroll
  for (int j = 0; j < 4; ++j) if (val[j]) mx = fmaxf(mx, v2[j]);
  mx = blockMaxF(mx, shf, lane, wid);
  sm = 0.f;
#pragma unroll
  for (int j = 0; j < 4; ++j) { float e = val[j] ? __expf(v2[j] - mx) : 0.f; v2[j] = e; sm += e; }
  sm = blockSumF(sm, shf, lane, wid);
  const float inv2 = 1.f / sm;
  const float w0 = fc_w[0], w1 = fc_w[1], fb = fc_b[0];
#pragma unroll
  for (int j = 0; j < 4; ++j) v1[j] = w0 * (v1[j] * inv1) + w1 * (v2[j] * inv2) + fb;
  mx = -FLT_MAX;
#pragma unroll
  for (int j = 0; j < 4; ++j) if (val[j]) mx = fmaxf(mx, v1[j]);
  mx = blockMaxF(mx, shf, lane, wid);
  sm = 0.f;
#pragma unroll
  for (int j = 0; j < 4; ++j) { float e = val[j] ? __expf(v1[j] - mx) : 0.f; v1[j] = e; sm += e; }
  sm = blockSumF(sm, shf, lane, wid);
  const float inv3 = 1.f / sm;

  unsigned ui[4];
#pragma unroll
  for (int j = 0; j < 4; ++j) ui[j] = val[j] ? __float_as_uint(v1[j]) : 0u;
  unsigned lo = 0u;
  for (int bit = 30; bit >= 0; --bit) {
    unsigned cand = lo | (1u << bit);
    int lc = 0;
#pragma unroll
    for (int j = 0; j < 4; ++j) lc += (ui[j] >= cand) ? 1 : 0;
    int cnt = blockSumI(lc, shi, lane, wid);
    if (cnt >= K_) lo = cand;
  }
  int gl = 0;
#pragma unroll
  for (int j = 0; j < 4; ++j) gl += (ui[j] > lo) ? 1 : 0;
  const int G = blockSumI(gl, shi, lane, wid);
  const int take = K_ - G;  // ties kept by smallest index (lax.top_k stability)

  ushortT* __restrict__ aT = adjT + (size_t)b * NP_ * NP_;
  int base = 0;
  for (int j = 0; j < 4; ++j) {
    bool eq = val[j] && (ui[j] == lo);
    unsigned long long ball = __ballot(eq ? 1 : 0);
    if (lane == 0) shi[wid] = __popcll(ball);
    __syncthreads();
    int wpre = 0, tot = 0;
#pragma unroll
    for (int w = 0; w < 4; ++w) { int cw = shi[w]; if (w < wid) wpre += cw; tot += cw; }
    __syncthreads();
    int lpre = __builtin_amdgcn_mbcnt_hi((unsigned)(ball >> 32),
                                         __builtin_amdgcn_mbcnt_lo((unsigned)ball, 0u));
    int rank = base + wpre + lpre;
    bool keep = val[j] && ((ui[j] > lo) || (eq && rank < take));
    int m = j * 256 + tid;
    if (val[j]) aT[(size_t)m * NP_ + n] = keep ? f2bf(v1[j] * inv3) : (ushortT)0;
    base += tot;
  }
}

// GEMM1: D[r=(t,c)][m] = sum_n hb[r][n]*adjT[m][n].  Writes:
//  - g1std[r][m] (bf16 std layout, m-pad ZEROED -> no memset needed)
//  - gk1[b][node][t][c]  (transposed via LDS round-trip)
__global__ __launch_bounds__(256) void k_diffm1(const ushortT* __restrict__ A,
                                                const ushortT* __restrict__ Bt,
                                                ushortT* __restrict__ Dstd,
                                                ushortT* __restrict__ gk1) {
  __shared__ ushortT lds[16384];  // dbuf; reused as 128x128 TLDS
  const int tid = threadIdx.x, l = tid & 63, w = tid >> 6;
  const int wr = w >> 1, wc = w & 1;
  const int m0 = blockIdx.x * 128, r0 = blockIdx.y * 128;
  const int b = blockIdx.z;
  const ushortT* __restrict__ Ab = A + (size_t)b * R_ * NP_;
  const ushortT* __restrict__ Bb = Bt + (size_t)b * NP_ * NP_;

  f32x4 acc[4][4];
#pragma unroll
  for (int i = 0; i < 4; ++i)
#pragma unroll
    for (int j = 0; j < 4; ++j) acc[i][j] = f32x4{0.f, 0.f, 0.f, 0.f};

  stage_tile(Ab, r0, 0, NP_, lds, w, l);
  stage_tile(Bb, m0, 0, NP_, lds + 8192, w, l);
  asm volatile("s_waitcnt vmcnt(0)" ::: "memory");
  __syncthreads();

  const int kg = l >> 4, rl = l & 15;
  for (int kt = 0; kt < 28; ++kt) {
    const int pb = kt & 1;
    if (kt < 27) {
      stage_tile(Ab, r0, (kt + 1) * 32, NP_, lds + (pb ^ 1) * 4096, w, l);
      stage_tile(Bb, m0, (kt + 1) * 32, NP_, lds + 8192 + (pb ^ 1) * 4096, w, l);
    }
    bf16x8 af[4], bfr[4];
#pragma unroll
    for (int fi = 0; fi < 4; ++fi)
      af[fi] = *(const bf16x8*)&lds[pb * 4096 + frag_u(wr * 64 + fi * 16 + rl, kg) * 8];
#pragma unroll
    for (int fj = 0; fj < 4; ++fj)
      bfr[fj] = *(const bf16x8*)&lds[8192 + pb * 4096 + frag_u(wc * 64 + fj * 16 + rl, kg) * 8];
#pragma unroll
    for (int fi = 0; fi < 4; ++fi)
#pragma unroll
      for (int fj = 0; fj < 4; ++fj)
        acc[fi][fj] = __builtin_amdgcn_mfma_f32_16x16x32_bf16(af[fi], bfr[fj], acc[fi][fj], 0, 0, 0);
    asm volatile("s_waitcnt vmcnt(0)" ::: "memory");
    __syncthreads();
  }

  // std epilogue: write full NP cols, zeroing m-pad (GEMM2 contracts over these cols)
#pragma unroll
  for (int fj = 0; fj < 4; ++fj) {
    int m = m0 + wc * 64 + fj * 16 + rl;
    bool vm = (m < N_);
#pragma unroll
    for (int fi = 0; fi < 4; ++fi)
#pragma unroll
      for (int v = 0; v < 4; ++v) {
        int r = r0 + wr * 64 + fi * 16 + kg * 4 + v;
        Dstd[(size_t)r * NP_ + m] = vm ? f2bf(acc[fi][fj][v]) : (ushortT)0;
      }
  }

  // transposed epilogue: acc -> TLDS[m_local][c_local] (XOR-swizzled) -> gk1 rows
  const int t = blockIdx.y;  // rows are (t,c) so r-block == t
#pragma unroll
  for (int fi = 0; fi < 4; ++fi)
#pragma unroll
    for (int fj = 0; fj < 4; ++fj) {
      int cb = wr * 64 + fi * 16 + kg * 4;   // c_local, 4 consecutive via v
      int mm = wc * 64 + fj * 16 + rl;       // m_local (node)
      ushort4 pk;
      pk.x = f2bf(acc[fi][fj][0]); pk.y = f2bf(acc[fi][fj][1]);
      pk.z = f2bf(acc[fi][fj][2]); pk.w = f2bf(acc[fi][fj][3]);
      *(ushort4*)((char*)lds + mm * 256 + ((cb * 2) ^ ((mm & 7) << 4))) = pk;
    }
  __syncthreads();
  ushortT* __restrict__ gkb = gk1 + (((size_t)b * NP_ + m0) * T_ + t) * C_;
#pragma unroll
  for (int i = 0; i < 8; ++i) {
    int slot = i * 256 + tid;
    int mm = slot >> 4, u = slot & 15;
    uint4 vv = *(const uint4*)((const char*)lds + mm * 256 + ((u ^ (mm & 7)) << 4));
    *(uint4*)(gkb + (size_t)mm * (T_ * C_) + u * 8) = vv;  // 16 lanes -> 256B contiguous
  }
}

// GEMM2 (reformulated): per (b,t): D[m][c] = sum_n adjT[m][n] * g1std[(t,c)][n]
// -> writes gk2[b][node][t][c] directly (c-contiguous 32B runs, no TLDS pass)
__global__ __launch_bounds__(256) void k_diff2(const ushortT* __restrict__ adjT,
                                               const ushortT* __restrict__ g1,
                                               ushortT* __restrict__ gk2) {
  __shared__ ushortT lds[16384];
  const int tid = threadIdx.x, l = tid & 63, w = tid >> 6;
  const int wr = w >> 1, wc = w & 1;
  const int m0 = blockIdx.x * 128, t = blockIdx.y, b = blockIdx.z;
  const ushortT* __restrict__ Ab = adjT + (size_t)b * NP_ * NP_;
  const ushortT* __restrict__ Bb = g1 + (size_t)b * R_ * NP_;

  f32x4 acc[4][4];
#pragma unroll
  for (int i = 0; i < 4; ++i)
#pragma unroll
    for (int j = 0; j < 4; ++j) acc[i][j] = f32x4{0.f, 0.f, 0.f, 0.f};

  stage_tile(Ab, m0, 0, NP_, lds, w, l);
  stage_tile(Bb, t * C_, 0, NP_, lds + 8192, w, l);
  asm volatile("s_waitcnt vmcnt(0)" ::: "memory");
  __syncthreads();

  const int kg = l >> 4, rl = l & 15;
  for (int kt = 0; kt < 28; ++kt) {
    const int pb = kt & 1;
    if (kt < 27) {
      stage_tile(Ab, m0, (kt + 1) * 32, NP_, lds + (pb ^ 1) * 4096, w, l);
      stage_tile(Bb, t * C_, (kt + 1) * 32, NP_, lds + 8192 + (pb ^ 1) * 4096, w, l);
    }
    bf16x8 af[4], bfr[4];
#pragma unroll
    for (int fi = 0; fi < 4; ++fi)
      af[fi] = *(const bf16x8*)&lds[pb * 4096 + frag_u(wr * 64 + fi * 16 + rl, kg) * 8];
#pragma unroll
    for (int fj = 0; fj < 4; ++fj)
      bfr[fj] = *(const bf16x8*)&lds[8192 + pb * 4096 + frag_u(wc * 64 + fj * 16 + rl, kg) * 8];
#pragma unroll
    for (int fi = 0; fi < 4; ++fi)
#pragma unroll
      for (int fj = 0; fj < 4; ++fj)
        acc[fi][fj] = __builtin_amdgcn_mfma_f32_16x16x32_bf16(af[fi], bfr[fj], acc[fi][fj], 0, 0, 0);
    asm volatile("s_waitcnt vmcnt(0)" ::: "memory");
    __syncthreads();
  }

  // epilogue: rows m (node), cols c -> gk2[((b*NP+m)*T+t)*C + c]
#pragma unroll
  for (int fj = 0; fj < 4; ++fj) {
    int c = wc * 64 + fj * 16 + rl;
#pragma unroll
    for (int fi = 0; fi < 4; ++fi)
#pragma unroll
      for (int v = 0; v < 4; ++v) {
        int m = m0 + wr * 64 + fi * 16 + kg * 4 + v;
        if (m < N_)
          gk2[(((size_t)b * NP_ + m) * T_ + t) * C_ + c] = f2bf(acc[fi][fj][v]);
      }
  }
}

// ------- out[b][o][m] = (sum_i W[o][i]*[gk1;gk2][b][m][i] + gcn_b[o])*emb[o] + x -------
// m = node*T + t flat; fully coalesced loads/stores along m.
__global__ __launch_bounds__(256) void k_outm(const ushortT* __restrict__ Wb,
                                              const ushortT* __restrict__ gk1,
                                              const ushortT* __restrict__ gk2,
                                              const float* __restrict__ gcn_b,
                                              const float* __restrict__ emb,
                                              const float* __restrict__ x,
                                              float* __restrict__ out) {
  __shared__ ushortT lds[16384];
  const int tid = threadIdx.x, l = tid & 63, w = tid >> 6;
  const int wr = w >> 1, wc = w & 1;
  const int m0 = blockIdx.x * 128;
  const int b = blockIdx.y;
  const ushortT* __restrict__ B1 = gk1 + (size_t)b * NPT_ * C_;
  const ushortT* __restrict__ B2 = gk2 + (size_t)b * NPT_ * C_;

  f32x4 acc[4][4];
#pragma unroll
  for (int i = 0; i < 4; ++i)
#pragma unroll
    for (int j = 0; j < 4; ++j) acc[i][j] = f32x4{0.f, 0.f, 0.f, 0.f};

  stage_tile(Wb, 0, 0, KI_, lds, w, l);
  stage_tile(B1, m0, 0, C_, lds + 8192, w, l);
  asm volatile("s_waitcnt vmcnt(0)" ::: "memory");
  __syncthreads();

  const int kg = l >> 4, rl = l & 15;
  for (int kt = 0; kt < 8; ++kt) {
    const int pb = kt & 1;
    if (kt < 7) {
      const int nk = kt + 1;
      stage_tile(Wb, 0, nk * 32, KI_, lds + (pb ^ 1) * 4096, w, l);
      if (nk < 4) stage_tile(B1, m0, nk * 32, C_, lds + 8192 + (pb ^ 1) * 4096, w, l);
      else        stage_tile(B2, m0, (nk - 4) * 32, C_, lds + 8192 + (pb ^ 1) * 4096, w, l);
    }
    bf16x8 af[4], bfr[4];
#pragma unroll
    for (int fi = 0; fi < 4; ++fi)
      af[fi] = *(const bf16x8*)&lds[pb * 4096 + frag_u(wr * 64 + fi * 16 + rl, kg) * 8];
#pragma unroll
    for (int fj = 0; fj < 4; ++fj)
      bfr[fj] = *(const bf16x8*)&lds[8192 + pb * 4096 + frag_u(wc * 64 + fj * 16 + rl, kg) * 8];
#pragma unroll
    for (int fi = 0; fi < 4; ++fi)
#pragma unroll
      for (int fj = 0; fj < 4; ++fj)
        acc[fi][fj] = __builtin_amdgcn_mfma_f32_16x16x32_bf16(af[fi], bfr[fj], acc[fi][fj], 0, 0, 0);
    asm volatile("s_waitcnt vmcnt(0)" ::: "memory");
    __syncthreads();
  }

#pragma unroll
  for (int fj = 0; fj < 4; ++fj) {
    int m = m0 + wc * 64 + fj * 16 + rl;
    if (m < NT_) {
#pragma unroll
      for (int fi = 0; fi < 4; ++fi) {
#pragma unroll
        for (int v = 0; v < 4; ++v) {
          int o = wr * 64 + fi * 16 + kg * 4 + v;
          size_t off = ((size_t)b * C_ + o) * NT_ + m;
          out[off] = (acc[fi][fj][v] + gcn_b[o]) * emb[o] + x[off];
        }
      }
    }
  }
}

extern "C" void kernel_launch(void* const* d_in, const int* in_sizes, int n_in,
                              void* d_out, int out_size, void* d_ws, size_t ws_size,
                              hipStream_t stream) {
  const float* x      = (const float*)d_in[0];
  const float* conv_w = (const float*)d_in[1];
  const float* conv_b = (const float*)d_in[2];
  const float* memory = (const float*)d_in[3];
  const float* fc_w   = (const float*)d_in[4];
  const float* fc_b   = (const float*)d_in[5];
  const float* gcn_w  = (const float*)d_in[6];
  const float* gcn_b  = (const float*)d_in[7];
  const float* emb    = (const float*)d_in[8];
  float* out = (float*)d_out;

  // workspace (all bf16 now). Aliases: g1std<-xTb (dead after convm),
  // gk1<-S1+S2 (dead after adj), gk2<-hb (dead after diffm1). Peak ~338 MB.
  char* p = (char*)d_ws;
  ushortT* xTb     = (ushortT*)p;  p += (size_t)B_ * T_ * NP_ * C_ * 2;   // 88.1 MB
  ushortT* hb      = (ushortT*)p;  p += (size_t)B_ * R_ * NP_ * 2;        // 88.1 MB
  ushortT* xsT     = (ushortT*)p;  p += (size_t)B_ * NP_ * C_ * 2;        //  7.3 MB
  ushortT* S1b     = (ushortT*)p;  p += (size_t)B_ * NP_ * NP_ * 2;       // 51.4 MB
  ushortT* S2b     = (ushortT*)p;  p += (size_t)B_ * NP_ * NP_ * 2;       // 51.4 MB
  ushortT* adjT    = (ushortT*)p;  p += (size_t)B_ * NP_ * NP_ * 2;       // 51.4 MB
  ushortT* conv_wb = (ushortT*)p;  p += C_ * C_ * 2;
  ushortT* gcn_wb  = (ushortT*)p;  p += C_ * KI_ * 2;
  ushortT* memT    = (ushortT*)p;  p += (size_t)NP_ * C_ * 2;
  ushortT* g1std   = xTb;   // B*R*NP*2   = 88.1 MB (== xTb size)
  ushortT* gk1     = S1b;   // B*NPT*C*2  = 88.1 MB <= S1+S2 (102.8)
  ushortT* gk2     = hb;    // B*NPT*C*2  = 88.1 MB (== hb size)

  k_transpose<<<dim3(512), dim3(256), 0, stream>>>(conv_w, gcn_w, memory, conv_wb, gcn_wb, memT);
  k_xT<<<dim3(332, 4, B_), dim3(256), 0, stream>>>(x, xTb);
  k_convm<<<dim3(7, T_, B_), dim3(256), 0, stream>>>(conv_wb, xTb, conv_b, hb);
  k_xsT2<<<dim3(28, 4, B_), dim3(256), 0, stream>>>(hb, xsT);
  k_scoresm<<<dim3(7, 7, B_), dim3(256), 0, stream>>>(xsT, memT, S1b, S2b);
  k_adj<<<dim3(N_, B_), dim3(256), 0, stream>>>(S1b, S2b, fc_w, fc_b, adjT);
  k_diffm1<<<dim3(7, T_, B_), dim3(256), 0, stream>>>(hb, adjT, g1std, gk1);
  k_diff2<<<dim3(7, T_, B_), dim3(256), 0, stream>>>(adjT, g1std, gk2);
  k_outm<<<dim3(84, B_), dim3(256), 0, stream>>>(gcn_wb, gk1, gk2, gcn_b, emb, x, out);
}

// Round 8
// 1130.683 us; speedup vs baseline: 6.7054x; 1.2674x over previous
//
#include <hip/hip_runtime.h>
#include <hip/hip_bf16.h>
#include <float.h>

#define B_ 32
#define C_ 128
#define N_ 883
#define T_ 12
#define K_ 706        // int(883*0.8)
#define NP_ 896       // N padded to multiple of 32
#define R_ 1536       // C_*T_
#define KI_ 256       // k_out contraction size (2*C_)
#define NT_ 10596     // N_*T_
#define NPT_ 10752    // NP_*T_
#define SCALE_ 0.08838834764831845f  // 1/sqrt(128)

typedef unsigned short ushortT;
typedef unsigned int uintT;
typedef float f32x4 __attribute__((ext_vector_type(4)));
typedef __bf16 bf16x8 __attribute__((ext_vector_type(8)));

__device__ __forceinline__ ushortT f2bf(float f) {
  union { __hip_bfloat16 h; ushortT u; } cv; cv.h = __float2bfloat16(f); return cv.u;
}
__device__ __forceinline__ float bf2f(ushortT u) {
  union { __hip_bfloat16 h; ushortT u; } cv; cv.u = u; return __bfloat162float(cv.h);
}

// ---------------- wave (64-lane) reductions, barrier-free ----------------
__device__ __forceinline__ float wmaxf(float v) {
#pragma unroll
  for (int o = 32; o; o >>= 1) v = fmaxf(v, __shfl_xor(v, o));
  return v;
}
__device__ __forceinline__ float wsumf(float v) {
#pragma unroll
  for (int o = 32; o; o >>= 1) v += __shfl_xor(v, o);
  return v;
}
__device__ __forceinline__ int mbcnt64(unsigned long long m) {
  return __builtin_amdgcn_mbcnt_hi((unsigned)(m >> 32),
                                   __builtin_amdgcn_mbcnt_lo((unsigned)m, 0u));
}

// -------- weight prep: conv_wb (bf16), gcn_wb (bf16), memT (bf16 transpose) --------
__global__ void k_transpose(const float* __restrict__ conv_w, const float* __restrict__ gcn_w,
                            const float* __restrict__ mem,
                            ushortT* __restrict__ conv_wb, ushortT* __restrict__ gcn_wb,
                            ushortT* __restrict__ memT) {
  int idx = blockIdx.x * 256 + threadIdx.x;
  if (idx < C_ * C_) {           // conv_wb[o][c] = bf16(conv_w[o][c]) (k=c contiguous)
    conv_wb[idx] = f2bf(conv_w[idx]);
  }
  if (idx < C_ * KI_) {          // gcn_wb[o][i] = bf16(gcn_w[o][i])
    gcn_wb[idx] = f2bf(gcn_w[idx]);
  }
  if (idx < C_ * N_) {           // memT[m][c] = bf16(mem[c][m])
    int c = idx / N_, m = idx % N_;
    memT[m * C_ + c] = f2bf(mem[idx]);
  }
}

// ------- xTb[b][t][n][c] = bf16(x[b][c][n][t])  (LDS 32x32 transpose, both sides coalesced)
__global__ __launch_bounds__(256) void k_xT(const float* __restrict__ x,
                                            ushortT* __restrict__ xTb) {
  __shared__ float lt[32][33];
  const int tx = threadIdx.x & 31, ty = threadIdx.x >> 5;   // ty in [0,8)
  const int m0 = blockIdx.x * 32, c0 = blockIdx.y * 32, b = blockIdx.z;
  const float* __restrict__ xb = x + (size_t)b * C_ * NT_;
#pragma unroll
  for (int i = 0; i < 4; ++i) {
    int c = c0 + ty + i * 8, m = m0 + tx;
    lt[ty + i * 8][tx] = (m < NT_) ? xb[(size_t)c * NT_ + m] : 0.f;
  }
  __syncthreads();
  ushortT* __restrict__ ob = xTb + (size_t)b * T_ * NP_ * C_;
#pragma unroll
  for (int i = 0; i < 4; ++i) {
    int m = m0 + ty + i * 8;
    if (m < NT_) {
      int n = m / T_, t = m - n * T_;
      ob[((size_t)t * NP_ + n) * C_ + c0 + tx] = f2bf(lt[tx][ty + i * 8]);
    }
  }
}

// ---------------- shared MFMA GEMM machinery ----------------
#define GLOAD16(gp, lp) __builtin_amdgcn_global_load_lds( \
    (const __attribute__((address_space(1))) unsigned int*)(gp), \
    (__attribute__((address_space(3))) unsigned int*)(lp), 16, 0, 0)

// bijective 16B-unit swizzle: rows spread across bank-quads (2-way = free)
__device__ __forceinline__ int frag_u(int row, int kg) {
  int bu = row >> 1;
  int inner = ((row & 1) << 2) | kg;
  return (bu << 3) | (inner ^ (bu & 7));
}

// stage 128 rows x 32 k bf16 (8KB), row stride rstride elements
__device__ __forceinline__ void stage_tile(const ushortT* __restrict__ gbase, int row0, int k0,
                                           int rstride, ushortT* lds, int w, int l) {
#pragma unroll
  for (int i = 0; i < 2; ++i) {
    int u = w * 128 + i * 64 + l;
    int bu = u >> 3;
    int inner = (u & 7) ^ (bu & 7);
    int row = bu * 2 + (inner >> 2);
    int kg = inner & 3;
    const ushortT* src = gbase + (size_t)(row0 + row) * rstride + k0 + kg * 8;
    GLOAD16(src, lds + u * 8);
  }
}

// ------- hb[(t,o)][n] = bf16(conv_w . x + conv_b)  via MFMA, n-pad zeroed -------
__global__ __launch_bounds__(256) void k_convm(const ushortT* __restrict__ Wb,
                                               const ushortT* __restrict__ xTb,
                                               const float* __restrict__ conv_b,
                                               ushortT* __restrict__ hb) {
  __shared__ ushortT lds[16384];
  const int tid = threadIdx.x, l = tid & 63, w = tid >> 6;
  const int wr = w >> 1, wc = w & 1;
  const int n0 = blockIdx.x * 128, t = blockIdx.y, b = blockIdx.z;
  const ushortT* __restrict__ Bb = xTb + ((size_t)b * T_ + t) * NP_ * C_;

  f32x4 acc[4][4];
#pragma unroll
  for (int i = 0; i < 4; ++i)
#pragma unroll
    for (int j = 0; j < 4; ++j) acc[i][j] = f32x4{0.f, 0.f, 0.f, 0.f};

  stage_tile(Wb, 0, 0, C_, lds, w, l);
  stage_tile(Bb, n0, 0, C_, lds + 8192, w, l);
  asm volatile("s_waitcnt vmcnt(0)" ::: "memory");
  __syncthreads();

  const int kg = l >> 4, rl = l & 15;
  for (int kt = 0; kt < 4; ++kt) {
    const int pb = kt & 1;
    if (kt < 3) {
      stage_tile(Wb, 0, (kt + 1) * 32, C_, lds + (pb ^ 1) * 4096, w, l);
      stage_tile(Bb, n0, (kt + 1) * 32, C_, lds + 8192 + (pb ^ 1) * 4096, w, l);
    }
    bf16x8 af[4], bfr[4];
#pragma unroll
    for (int fi = 0; fi < 4; ++fi)
      af[fi] = *(const bf16x8*)&lds[pb * 4096 + frag_u(wr * 64 + fi * 16 + rl, kg) * 8];
#pragma unroll
    for (int fj = 0; fj < 4; ++fj)
      bfr[fj] = *(const bf16x8*)&lds[8192 + pb * 4096 + frag_u(wc * 64 + fj * 16 + rl, kg) * 8];
#pragma unroll
    for (int fi = 0; fi < 4; ++fi)
#pragma unroll
      for (int fj = 0; fj < 4; ++fj)
        acc[fi][fj] = __builtin_amdgcn_mfma_f32_16x16x32_bf16(af[fi], bfr[fj], acc[fi][fj], 0, 0, 0);
    asm volatile("s_waitcnt vmcnt(0)" ::: "memory");
    __syncthreads();
  }

  ushortT* __restrict__ hbb = hb + (size_t)b * R_ * NP_ + (size_t)t * C_ * NP_;
#pragma unroll
  for (int fj = 0; fj < 4; ++fj) {
    int n = n0 + wc * 64 + fj * 16 + rl;
    bool vn = (n < N_);
#pragma unroll
    for (int fi = 0; fi < 4; ++fi) {
      int ob = wr * 64 + fi * 16 + kg * 4;
#pragma unroll
      for (int v = 0; v < 4; ++v) {
        float cb = conv_b[ob + v];
        hbb[(size_t)(ob + v) * NP_ + n] = vn ? f2bf(acc[fi][fj][v] + cb) : (ushortT)0;
      }
    }
  }
}

// ---- xsT[b][n][c] = bf16(sum_t hb[(t,c)][n])  (LDS 32x32 transpose; pad rows -> 0) ----
__global__ __launch_bounds__(256) void k_xsT2(const ushortT* __restrict__ hb,
                                              ushortT* __restrict__ xsT) {
  __shared__ float lt[32][33];
  const int tx = threadIdx.x & 31, ty = threadIdx.x >> 5;
  const int n0 = blockIdx.x * 32, c0 = blockIdx.y * 32, b = blockIdx.z;
  const ushortT* __restrict__ hbb = hb + (size_t)b * R_ * NP_;
#pragma unroll
  for (int i = 0; i < 4; ++i) {
    int c = c0 + ty + i * 8, n = n0 + tx;
    float s = 0.f;
#pragma unroll
    for (int t = 0; t < T_; ++t)
      s += bf2f(hbb[((size_t)t * C_ + c) * NP_ + n]);
    lt[ty + i * 8][tx] = s;   // hb n-pad is zero -> pad sums are 0
  }
  __syncthreads();
  ushortT* __restrict__ ob = xsT + (size_t)b * NP_ * C_;
#pragma unroll
  for (int i = 0; i < 4; ++i) {
    int n = n0 + ty + i * 8;
    ob[(size_t)n * C_ + c0 + tx] = f2bf(lt[tx][ty + i * 8]);
  }
}

// ---- S1 = relu(scale * xsT . memT^T), S2 = relu(scale * xsT . xsT^T), [n][m] stride NP ----
__global__ __launch_bounds__(256) void k_scoresm(const ushortT* __restrict__ xsT,
                                                 const ushortT* __restrict__ memT,
                                                 ushortT* __restrict__ S1,
                                                 ushortT* __restrict__ S2) {
  __shared__ ushortT lds[24576];
  const int tid = threadIdx.x, l = tid & 63, w = tid >> 6;
  const int wr = w >> 1, wc = w & 1;
  const int m0 = blockIdx.x * 128, n0 = blockIdx.y * 128;
  const int b = blockIdx.z;
  const ushortT* __restrict__ Ab = xsT + (size_t)b * NP_ * C_;

  f32x4 acc1[4][4], acc2[4][4];
#pragma unroll
  for (int i = 0; i < 4; ++i)
#pragma unroll
    for (int j = 0; j < 4; ++j) { acc1[i][j] = f32x4{0,0,0,0}; acc2[i][j] = f32x4{0,0,0,0}; }

  stage_tile(Ab, n0, 0, C_, lds, w, l);
  stage_tile(memT, m0, 0, C_, lds + 8192, w, l);
  stage_tile(Ab, m0, 0, C_, lds + 16384, w, l);
  asm volatile("s_waitcnt vmcnt(0)" ::: "memory");
  __syncthreads();

  const int kg = l >> 4, rl = l & 15;
  for (int kt = 0; kt < 4; ++kt) {
    const int pb = kt & 1;
    if (kt < 3) {
      stage_tile(Ab, n0, (kt + 1) * 32, C_, lds + (pb ^ 1) * 4096, w, l);
      stage_tile(memT, m0, (kt + 1) * 32, C_, lds + 8192 + (pb ^ 1) * 4096, w, l);
      stage_tile(Ab, m0, (kt + 1) * 32, C_, lds + 16384 + (pb ^ 1) * 4096, w, l);
    }
    bf16x8 af[4], b1[4], b2[4];
#pragma unroll
    for (int fi = 0; fi < 4; ++fi)
      af[fi] = *(const bf16x8*)&lds[pb * 4096 + frag_u(wr * 64 + fi * 16 + rl, kg) * 8];
#pragma unroll
    for (int fj = 0; fj < 4; ++fj) {
      b1[fj] = *(const bf16x8*)&lds[8192 + pb * 4096 + frag_u(wc * 64 + fj * 16 + rl, kg) * 8];
      b2[fj] = *(const bf16x8*)&lds[16384 + pb * 4096 + frag_u(wc * 64 + fj * 16 + rl, kg) * 8];
    }
#pragma unroll
    for (int fi = 0; fi < 4; ++fi)
#pragma unroll
      for (int fj = 0; fj < 4; ++fj) {
        acc1[fi][fj] = __builtin_amdgcn_mfma_f32_16x16x32_bf16(af[fi], b1[fj], acc1[fi][fj], 0, 0, 0);
        acc2[fi][fj] = __builtin_amdgcn_mfma_f32_16x16x32_bf16(af[fi], b2[fj], acc2[fi][fj], 0, 0, 0);
      }
    asm volatile("s_waitcnt vmcnt(0)" ::: "memory");
    __syncthreads();
  }

#pragma unroll
  for (int fj = 0; fj < 4; ++fj) {
    int m = m0 + wc * 64 + fj * 16 + rl;
#pragma unroll
    for (int fi = 0; fi < 4; ++fi)
#pragma unroll
      for (int v = 0; v < 4; ++v) {
        int n = n0 + wr * 64 + fi * 16 + kg * 4 + v;
        size_t off = ((size_t)b * NP_ + n) * NP_ + m;
        S1[off] = f2bf(fmaxf(acc1[fi][fj][v] * SCALE_, 0.f));
        S2[off] = f2bf(fmaxf(acc2[fi][fj][v] * SCALE_, 0.f));
      }
  }
}

// ---- per-(b,n) row: softmaxes, fc, softmax, topk -> adj row-major. ONE WAVE PER ROW,
// zero barriers: shfl-butterfly reductions + ballot/popc counting (no LDS, no syncthreads).
__global__ __launch_bounds__(256) void k_adj(const ushortT* __restrict__ S1,
                                             const ushortT* __restrict__ S2,
                                             const float* __restrict__ fc_w,
                                             const float* __restrict__ fc_b,
                                             ushortT* __restrict__ adj) {
  const int lane = threadIdx.x & 63, w = threadIdx.x >> 6;
  const int n = blockIdx.x * 4 + w;
  const int b = blockIdx.y;
  if (n >= N_) return;                       // wave-uniform exit (no barriers in kernel)
  const size_t roff = ((size_t)b * NP_ + n) * NP_;
  const uintT* __restrict__ S1u = (const uintT*)(S1 + roff);
  const uintT* __restrict__ S2u = (const uintT*)(S2 + roff);

  // 14 values/lane: slot j holds m = j*128 + lane*2 + {0,1}
  float v1[14], v2[14];
  bool val[14];
#pragma unroll
  for (int j = 0; j < 7; ++j) {
    uintT u1 = S1u[j * 64 + lane];
    uintT u2 = S2u[j * 64 + lane];
    int m0 = j * 128 + lane * 2;
    val[2 * j]     = (m0 < N_);
    val[2 * j + 1] = (m0 + 1 < N_);
    v1[2 * j]     = bf2f((ushortT)(u1 & 0xFFFF));
    v1[2 * j + 1] = bf2f((ushortT)(u1 >> 16));
    v2[2 * j]     = bf2f((ushortT)(u2 & 0xFFFF));
    v2[2 * j + 1] = bf2f((ushortT)(u2 >> 16));
  }
  // softmax over v1
  float mx = -FLT_MAX;
#pragma unroll
  for (int j = 0; j < 14; ++j) if (val[j]) mx = fmaxf(mx, v1[j]);
  mx = wmaxf(mx);
  float sm = 0.f;
#pragma unroll
  for (int j = 0; j < 14; ++j) { float e = val[j] ? __expf(v1[j] - mx) : 0.f; v1[j] = e; sm += e; }
  const float inv1 = 1.f / wsumf(sm);
  // softmax over v2
  mx = -FLT_MAX;
#pragma unroll
  for (int j = 0; j < 14; ++j) if (val[j]) mx = fmaxf(mx, v2[j]);
  mx = wmaxf(mx);
  sm = 0.f;
#pragma unroll
  for (int j = 0; j < 14; ++j) { float e = val[j] ? __expf(v2[j] - mx) : 0.f; v2[j] = e; sm += e; }
  const float inv2 = 1.f / wsumf(sm);
  // fc combine + softmax3 (exp values kept in v1; invalid lanes -> exactly 0)
  const float w0 = fc_w[0], w1 = fc_w[1], fb = fc_b[0];
#pragma unroll
  for (int j = 0; j < 14; ++j) v1[j] = w0 * (v1[j] * inv1) + w1 * (v2[j] * inv2) + fb;
  mx = -FLT_MAX;
#pragma unroll
  for (int j = 0; j < 14; ++j) if (val[j]) mx = fmaxf(mx, v1[j]);
  mx = wmaxf(mx);
  sm = 0.f;
#pragma unroll
  for (int j = 0; j < 14; ++j) { float e = val[j] ? __expf(v1[j] - mx) : 0.f; v1[j] = e; sm += e; }
  const float inv3 = 1.f / wsumf(sm);

  // top-K threshold via bitwise binary search; counts by ballot+popc (uniform scalars).
  // keys = float bits of exp values (positive; invalid are exactly 0). e <= 1.0 -> bit30=0.
  unsigned lo = 0u;
  for (int bit = 29; bit >= 0; --bit) {
    unsigned cand = lo | (1u << bit);
    int cnt = 0;
#pragma unroll
    for (int j = 0; j < 14; ++j)
      cnt += __popcll(__ballot(__float_as_uint(v1[j]) >= cand));
    if (cnt >= K_) lo = cand;
  }
  int gcount = 0;
#pragma unroll
  for (int j = 0; j < 14; ++j)
    gcount += __popcll(__ballot(__float_as_uint(v1[j]) > lo));
  const int take = K_ - gcount;  // ties (== lo) kept by smallest m (lax.top_k stability)

  uintT* __restrict__ arow = (uintT*)(adj + roff);
  int base = 0;
#pragma unroll
  for (int j = 0; j < 7; ++j) {
    unsigned u0 = __float_as_uint(v1[2 * j]);
    unsigned u1v = __float_as_uint(v1[2 * j + 1]);
    bool eq0 = (u0 == lo), eq1 = (u1v == lo);
    unsigned long long b0 = __ballot(eq0);
    unsigned long long b1 = __ballot(eq1);
    int pre0 = base + mbcnt64(b0) + mbcnt64(b1);      // eq's at smaller m (lanes below, both pairs)
    int pre1 = pre0 + (eq0 ? 1 : 0);
    bool k0 = val[2 * j] && ((u0 > lo) || (eq0 && pre0 < take));
    bool k1 = val[2 * j + 1] && ((u1v > lo) || (eq1 && pre1 < take));
    ushortT o0 = k0 ? f2bf(v1[2 * j] * inv3) : (ushortT)0;
    ushortT o1 = k1 ? f2bf(v1[2 * j + 1] * inv3) : (ushortT)0;
    arow[j * 64 + lane] = (uintT)o0 | ((uintT)o1 << 16);   // coalesced 4B stores
    base += __popcll(b0) + __popcll(b1);
  }
}

// ---- adjT[b][m][n] = adj[b][n][m]  (LDS 32x32 bf16 tile transpose, both sides coalesced)
__global__ __launch_bounds__(256) void k_aT(const ushortT* __restrict__ adj,
                                            ushortT* __restrict__ adjT) {
  __shared__ ushortT lt[32][34];
  const int tx = threadIdx.x & 31, ty = threadIdx.x >> 5;
  const int m0 = blockIdx.x * 32, n0 = blockIdx.y * 32, b = blockIdx.z;
  const ushortT* __restrict__ ab = adj + (size_t)b * NP_ * NP_;
#pragma unroll
  for (int i = 0; i < 4; ++i)
    lt[ty + i * 8][tx] = ab[(size_t)(n0 + ty + i * 8) * NP_ + m0 + tx];
  __syncthreads();
  ushortT* __restrict__ ob = adjT + (size_t)b * NP_ * NP_;
#pragma unroll
  for (int i = 0; i < 4; ++i)
    ob[(size_t)(m0 + ty + i * 8) * NP_ + n0 + tx] = lt[tx][ty + i * 8];
}

// GEMM1: D[r=(t,c)][m] = sum_n hb[r][n]*adjT[m][n].  Writes:
//  - g1std[r][m] (bf16 std layout, m-pad ZEROED)
//  - gk1[b][node][t][c]  (transposed via LDS round-trip)
__global__ __launch_bounds__(256) void k_diffm1(const ushortT* __restrict__ A,
                                                const ushortT* __restrict__ Bt,
                                                ushortT* __restrict__ Dstd,
                                                ushortT* __restrict__ gk1) {
  __shared__ ushortT lds[16384];  // dbuf; reused as 128x128 TLDS
  const int tid = threadIdx.x, l = tid & 63, w = tid >> 6;
  const int wr = w >> 1, wc = w & 1;
  const int m0 = blockIdx.x * 128, r0 = blockIdx.y * 128;
  const int b = blockIdx.z;
  const ushortT* __restrict__ Ab = A + (size_t)b * R_ * NP_;
  const ushortT* __restrict__ Bb = Bt + (size_t)b * NP_ * NP_;

  f32x4 acc[4][4];
#pragma unroll
  for (int i = 0; i < 4; ++i)
#pragma unroll
    for (int j = 0; j < 4; ++j) acc[i][j] = f32x4{0.f, 0.f, 0.f, 0.f};

  stage_tile(Ab, r0, 0, NP_, lds, w, l);
  stage_tile(Bb, m0, 0, NP_, lds + 8192, w, l);
  asm volatile("s_waitcnt vmcnt(0)" ::: "memory");
  __syncthreads();

  const int kg = l >> 4, rl = l & 15;
  for (int kt = 0; kt < 28; ++kt) {
    const int pb = kt & 1;
    if (kt < 27) {
      stage_tile(Ab, r0, (kt + 1) * 32, NP_, lds + (pb ^ 1) * 4096, w, l);
      stage_tile(Bb, m0, (kt + 1) * 32, NP_, lds + 8192 + (pb ^ 1) * 4096, w, l);
    }
    bf16x8 af[4], bfr[4];
#pragma unroll
    for (int fi = 0; fi < 4; ++fi)
      af[fi] = *(const bf16x8*)&lds[pb * 4096 + frag_u(wr * 64 + fi * 16 + rl, kg) * 8];
#pragma unroll
    for (int fj = 0; fj < 4; ++fj)
      bfr[fj] = *(const bf16x8*)&lds[8192 + pb * 4096 + frag_u(wc * 64 + fj * 16 + rl, kg) * 8];
#pragma unroll
    for (int fi = 0; fi < 4; ++fi)
#pragma unroll
      for (int fj = 0; fj < 4; ++fj)
        acc[fi][fj] = __builtin_amdgcn_mfma_f32_16x16x32_bf16(af[fi], bfr[fj], acc[fi][fj], 0, 0, 0);
    asm volatile("s_waitcnt vmcnt(0)" ::: "memory");
    __syncthreads();
  }

#pragma unroll
  for (int fj = 0; fj < 4; ++fj) {
    int m = m0 + wc * 64 + fj * 16 + rl;
    bool vm = (m < N_);
#pragma unroll
    for (int fi = 0; fi < 4; ++fi)
#pragma unroll
      for (int v = 0; v < 4; ++v) {
        int r = r0 + wr * 64 + fi * 16 + kg * 4 + v;
        Dstd[(size_t)r * NP_ + m] = vm ? f2bf(acc[fi][fj][v]) : (ushortT)0;
      }
  }

  const int t = blockIdx.y;  // rows are (t,c) so r-block == t
#pragma unroll
  for (int fi = 0; fi < 4; ++fi)
#pragma unroll
    for (int fj = 0; fj < 4; ++fj) {
      int cb = wr * 64 + fi * 16 + kg * 4;
      int mm = wc * 64 + fj * 16 + rl;
      ushort4 pk;
      pk.x = f2bf(acc[fi][fj][0]); pk.y = f2bf(acc[fi][fj][1]);
      pk.z = f2bf(acc[fi][fj][2]); pk.w = f2bf(acc[fi][fj][3]);
      *(ushort4*)((char*)lds + mm * 256 + ((cb * 2) ^ ((mm & 7) << 4))) = pk;
    }
  __syncthreads();
  ushortT* __restrict__ gkb = gk1 + (((size_t)b * NP_ + m0) * T_ + t) * C_;
#pragma unroll
  for (int i = 0; i < 8; ++i) {
    int slot = i * 256 + tid;
    int mm = slot >> 4, u = slot & 15;
    uint4 vv = *(const uint4*)((const char*)lds + mm * 256 + ((u ^ (mm & 7)) << 4));
    *(uint4*)(gkb + (size_t)mm * (T_ * C_) + u * 8) = vv;
  }
}

// GEMM2: per (b,t): D[m][c] = sum_n adjT[m][n] * g1std[(t,c)][n] -> gk2[b][node][t][c]
__global__ __launch_bounds__(256) void k_diff2(const ushortT* __restrict__ adjT,
                                               const ushortT* __restrict__ g1,
                                               ushortT* __restrict__ gk2) {
  __shared__ ushortT lds[16384];
  const int tid = threadIdx.x, l = tid & 63, w = tid >> 6;
  const int wr = w >> 1, wc = w & 1;
  const int m0 = blockIdx.x * 128, t = blockIdx.y, b = blockIdx.z;
  const ushortT* __restrict__ Ab = adjT + (size_t)b * NP_ * NP_;
  const ushortT* __restrict__ Bb = g1 + (size_t)b * R_ * NP_;

  f32x4 acc[4][4];
#pragma unroll
  for (int i = 0; i < 4; ++i)
#pragma unroll
    for (int j = 0; j < 4; ++j) acc[i][j] = f32x4{0.f, 0.f, 0.f, 0.f};

  stage_tile(Ab, m0, 0, NP_, lds, w, l);
  stage_tile(Bb, t * C_, 0, NP_, lds + 8192, w, l);
  asm volatile("s_waitcnt vmcnt(0)" ::: "memory");
  __syncthreads();

  const int kg = l >> 4, rl = l & 15;
  for (int kt = 0; kt < 28; ++kt) {
    const int pb = kt & 1;
    if (kt < 27) {
      stage_tile(Ab, m0, (kt + 1) * 32, NP_, lds + (pb ^ 1) * 4096, w, l);
      stage_tile(Bb, t * C_, (kt + 1) * 32, NP_, lds + 8192 + (pb ^ 1) * 4096, w, l);
    }
    bf16x8 af[4], bfr[4];
#pragma unroll
    for (int fi = 0; fi < 4; ++fi)
      af[fi] = *(const bf16x8*)&lds[pb * 4096 + frag_u(wr * 64 + fi * 16 + rl, kg) * 8];
#pragma unroll
    for (int fj = 0; fj < 4; ++fj)
      bfr[fj] = *(const bf16x8*)&lds[8192 + pb * 4096 + frag_u(wc * 64 + fj * 16 + rl, kg) * 8];
#pragma unroll
    for (int fi = 0; fi < 4; ++fi)
#pragma unroll
      for (int fj = 0; fj < 4; ++fj)
        acc[fi][fj] = __builtin_amdgcn_mfma_f32_16x16x32_bf16(af[fi], bfr[fj], acc[fi][fj], 0, 0, 0);
    asm volatile("s_waitcnt vmcnt(0)" ::: "memory");
    __syncthreads();
  }

#pragma unroll
  for (int fj = 0; fj < 4; ++fj) {
    int c = wc * 64 + fj * 16 + rl;
#pragma unroll
    for (int fi = 0; fi < 4; ++fi)
#pragma unroll
      for (int v = 0; v < 4; ++v) {
        int m = m0 + wr * 64 + fi * 16 + kg * 4 + v;
        if (m < N_)
          gk2[(((size_t)b * NP_ + m) * T_ + t) * C_ + c] = f2bf(acc[fi][fj][v]);
      }
  }
}

// ------- out[b][o][m] = (sum_i W[o][i]*[gk1;gk2][b][m][i] + gcn_b[o])*emb[o] + x -------
__global__ __launch_bounds__(256) void k_outm(const ushortT* __restrict__ Wb,
                                              const ushortT* __restrict__ gk1,
                                              const ushortT* __restrict__ gk2,
                                              const float* __restrict__ gcn_b,
                                              const float* __restrict__ emb,
                                              const float* __restrict__ x,
                                              float* __restrict__ out) {
  __shared__ ushortT lds[16384];
  const int tid = threadIdx.x, l = tid & 63, w = tid >> 6;
  const int wr = w >> 1, wc = w & 1;
  const int m0 = blockIdx.x * 128;
  const int b = blockIdx.y;
  const ushortT* __restrict__ B1 = gk1 + (size_t)b * NPT_ * C_;
  const ushortT* __restrict__ B2 = gk2 + (size_t)b * NPT_ * C_;

  f32x4 acc[4][4];
#pragma unroll
  for (int i = 0; i < 4; ++i)
#pragma unroll
    for (int j = 0; j < 4; ++j) acc[i][j] = f32x4{0.f, 0.f, 0.f, 0.f};

  stage_tile(Wb, 0, 0, KI_, lds, w, l);
  stage_tile(B1, m0, 0, C_, lds + 8192, w, l);
  asm volatile("s_waitcnt vmcnt(0)" ::: "memory");
  __syncthreads();

  const int kg = l >> 4, rl = l & 15;
  for (int kt = 0; kt < 8; ++kt) {
    const int pb = kt & 1;
    if (kt < 7) {
      const int nk = kt + 1;
      stage_tile(Wb, 0, nk * 32, KI_, lds + (pb ^ 1) * 4096, w, l);
      if (nk < 4) stage_tile(B1, m0, nk * 32, C_, lds + 8192 + (pb ^ 1) * 4096, w, l);
      else        stage_tile(B2, m0, (nk - 4) * 32, C_, lds + 8192 + (pb ^ 1) * 4096, w, l);
    }
    bf16x8 af[4], bfr[4];
#pragma unroll
    for (int fi = 0; fi < 4; ++fi)
      af[fi] = *(const bf16x8*)&lds[pb * 4096 + frag_u(wr * 64 + fi * 16 + rl, kg) * 8];
#pragma unroll
    for (int fj = 0; fj < 4; ++fj)
      bfr[fj] = *(const bf16x8*)&lds[8192 + pb * 4096 + frag_u(wc * 64 + fj * 16 + rl, kg) * 8];
#pragma unroll
    for (int fi = 0; fi < 4; ++fi)
#pragma unroll
      for (int fj = 0; fj < 4; ++fj)
        acc[fi][fj] = __builtin_amdgcn_mfma_f32_16x16x32_bf16(af[fi], bfr[fj], acc[fi][fj], 0, 0, 0);
    asm volatile("s_waitcnt vmcnt(0)" ::: "memory");
    __syncthreads();
  }

#pragma unroll
  for (int fj = 0; fj < 4; ++fj) {
    int m = m0 + wc * 64 + fj * 16 + rl;
    if (m < NT_) {
#pragma unroll
      for (int fi = 0; fi < 4; ++fi) {
#pragma unroll
        for (int v = 0; v < 4; ++v) {
          int o = wr * 64 + fi * 16 + kg * 4 + v;
          size_t off = ((size_t)b * C_ + o) * NT_ + m;
          out[off] = (acc[fi][fj][v] + gcn_b[o]) * emb[o] + x[off];
        }
      }
    }
  }
}

extern "C" void kernel_launch(void* const* d_in, const int* in_sizes, int n_in,
                              void* d_out, int out_size, void* d_ws, size_t ws_size,
                              hipStream_t stream) {
  const float* x      = (const float*)d_in[0];
  const float* conv_w = (const float*)d_in[1];
  const float* conv_b = (const float*)d_in[2];
  const float* memory = (const float*)d_in[3];
  const float* fc_w   = (const float*)d_in[4];
  const float* fc_b   = (const float*)d_in[5];
  const float* gcn_w  = (const float*)d_in[6];
  const float* gcn_b  = (const float*)d_in[7];
  const float* emb    = (const float*)d_in[8];
  float* out = (float*)d_out;

  // workspace (all bf16). Aliases: g1std<-xTb (dead after convm),
  // gk1<-S1+S2 (dead after k_adj), gk2<-hb (dead after diffm1). Peak ~390 MB.
  char* p = (char*)d_ws;
  ushortT* xTb     = (ushortT*)p;  p += (size_t)B_ * T_ * NP_ * C_ * 2;   // 88.1 MB
  ushortT* hb      = (ushortT*)p;  p += (size_t)B_ * R_ * NP_ * 2;        // 88.1 MB
  ushortT* xsT     = (ushortT*)p;  p += (size_t)B_ * NP_ * C_ * 2;        //  7.3 MB
  ushortT* S1b     = (ushortT*)p;  p += (size_t)B_ * NP_ * NP_ * 2;       // 51.4 MB
  ushortT* S2b     = (ushortT*)p;  p += (size_t)B_ * NP_ * NP_ * 2;       // 51.4 MB
  ushortT* adjR    = (ushortT*)p;  p += (size_t)B_ * NP_ * NP_ * 2;       // 51.4 MB (row-major)
  ushortT* adjT    = (ushortT*)p;  p += (size_t)B_ * NP_ * NP_ * 2;       // 51.4 MB
  ushortT* conv_wb = (ushortT*)p;  p += C_ * C_ * 2;
  ushortT* gcn_wb  = (ushortT*)p;  p += C_ * KI_ * 2;
  ushortT* memT    = (ushortT*)p;  p += (size_t)NP_ * C_ * 2;
  ushortT* g1std   = xTb;   // B*R*NP*2   = 88.1 MB (== xTb size)
  ushortT* gk1     = S1b;   // B*NPT*C*2  = 88.1 MB <= S1+S2 (102.8)
  ushortT* gk2     = hb;    // B*NPT*C*2  = 88.1 MB (== hb size)

  k_transpose<<<dim3(512), dim3(256), 0, stream>>>(conv_w, gcn_w, memory, conv_wb, gcn_wb, memT);
  k_xT<<<dim3(332, 4, B_), dim3(256), 0, stream>>>(x, xTb);
  k_convm<<<dim3(7, T_, B_), dim3(256), 0, stream>>>(conv_wb, xTb, conv_b, hb);
  k_xsT2<<<dim3(28, 4, B_), dim3(256), 0, stream>>>(hb, xsT);
  k_scoresm<<<dim3(7, 7, B_), dim3(256), 0, stream>>>(xsT, memT, S1b, S2b);
  k_adj<<<dim3((N_ + 3) / 4, B_), dim3(256), 0, stream>>>(S1b, S2b, fc_w, fc_b, adjR);
  k_aT<<<dim3(28, 28, B_), dim3(256), 0, stream>>>(adjR, adjT);
  k_diffm1<<<dim3(7, T_, B_), dim3(256), 0, stream>>>(hb, adjT, g1std, gk1);
  k_diff2<<<dim3(7, T_, B_), dim3(256), 0, stream>>>(adjT, g1std, gk2);
  k_outm<<<dim3(84, B_), dim3(256), 0, stream>>>(gcn_wb, gk1, gk2, gcn_b, emb, x, out);
}